// Round 9
// baseline (98.350 us; speedup 1.0000x reference)
//
#include <hip/hip_runtime.h>
#include <math.h>

#define NKPT 17
#define BATCH 32
#define MROW 544          // BATCH*NKPT
#define MPAD 576          // 9*64

typedef unsigned short u16;
typedef _Float16 half8 __attribute__((ext_vector_type(8)));
typedef float f32x4 __attribute__((ext_vector_type(4)));

__device__ __forceinline__ u16 f2h(float f) {
    _Float16 h = (_Float16)f;
    u16 u; __builtin_memcpy(&u, &h, 2); return u;
}
__device__ __forceinline__ float h2f(u16 u) {
    _Float16 h; __builtin_memcpy(&h, &u, 2); return (float)h;
}

// ------------------------------------------------- GEMM -> fp16 parts -----
// BM=64, BN=64, BK=64, 256 threads (4 waves as 2x2 of 32x32), double-buffered
// LDS, one barrier per k-step. A: fp16 [MPAD][lda]. BT: fp16 [N][K].
// Split-K: part s stores DIRECTLY (fp16) to dst + s*MPAD*ldd. No atomics.
struct GDp {
    const u16* A; const u16* BT; const float* bias; u16* dst;
    int lda, ldd, K, N, ntiles, sk;
};
struct GPp { GDp d[4]; int blk0[5]; int nd; };

__global__ __launch_bounds__(256) void gemm_part(GPp P)
{
    __shared__ u16 sA[2][64][72];
    __shared__ u16 sB[2][64][72];
    int bid = blockIdx.x, gi = 0;
    while (gi + 1 < P.nd && bid >= P.blk0[gi + 1]) ++gi;
    const GDp g = P.d[gi];
    int local = bid - P.blk0[gi];
    const int nspan = g.ntiles * g.sk;
    const int mt = local / nspan;
    int rem = local - mt * nspan;
    const int nt = rem / g.sk;
    const int s  = rem - nt * g.sk;
    const int m0 = mt * 64, n0 = nt * 64;
    const int Kseg = g.K / g.sk;
    const int kbase = s * Kseg;

    const int t = threadIdx.x;
    const int l = t & 63, w = t >> 6, wr = w >> 1, wc = w & 1;
    const int row = t >> 2, kc = (t & 3) << 4;

    f32x4 acc[2][2];
    #pragma unroll
    for (int i = 0; i < 2; ++i)
        #pragma unroll
        for (int j = 0; j < 2; ++j) { f32x4 z = {0.f,0.f,0.f,0.f}; acc[i][j] = z; }

    const u16* ap = g.A  + (size_t)(m0 + row) * g.lda + kbase + kc;
    const u16* bp = g.BT + (size_t)(n0 + row) * g.K   + kbase + kc;
    uint4 ra0 = *(const uint4*)ap, ra1 = *(const uint4*)(ap + 8);
    uint4 rb0 = *(const uint4*)bp, rb1 = *(const uint4*)(bp + 8);
    *(uint4*)&sA[0][row][kc] = ra0; *(uint4*)&sA[0][row][kc + 8] = ra1;
    *(uint4*)&sB[0][row][kc] = rb0; *(uint4*)&sB[0][row][kc + 8] = rb1;
    __syncthreads();

    int cur = 0;
    for (int k0 = 0; k0 < Kseg; k0 += 64) {
        const bool nxt = (k0 + 64 < Kseg);
        if (nxt) {
            ra0 = *(const uint4*)(ap + k0 + 64); ra1 = *(const uint4*)(ap + k0 + 72);
            rb0 = *(const uint4*)(bp + k0 + 64); rb1 = *(const uint4*)(bp + k0 + 72);
        }
        #pragma unroll
        for (int ks = 0; ks < 64; ks += 32) {
            const int koff = ks + (l >> 4) * 8;
            half8 af0 = *(const half8*)&sA[cur][wr * 32 +      (l & 15)][koff];
            half8 af1 = *(const half8*)&sA[cur][wr * 32 + 16 + (l & 15)][koff];
            half8 bf0 = *(const half8*)&sB[cur][wc * 32 +      (l & 15)][koff];
            half8 bf1 = *(const half8*)&sB[cur][wc * 32 + 16 + (l & 15)][koff];
            acc[0][0] = __builtin_amdgcn_mfma_f32_16x16x32_f16(af0, bf0, acc[0][0], 0, 0, 0);
            acc[0][1] = __builtin_amdgcn_mfma_f32_16x16x32_f16(af0, bf1, acc[0][1], 0, 0, 0);
            acc[1][0] = __builtin_amdgcn_mfma_f32_16x16x32_f16(af1, bf0, acc[1][0], 0, 0, 0);
            acc[1][1] = __builtin_amdgcn_mfma_f32_16x16x32_f16(af1, bf1, acc[1][1], 0, 0, 0);
        }
        if (nxt) {
            int nb = cur ^ 1;
            *(uint4*)&sA[nb][row][kc] = ra0; *(uint4*)&sA[nb][row][kc + 8] = ra1;
            *(uint4*)&sB[nb][row][kc] = rb0; *(uint4*)&sB[nb][row][kc + 8] = rb1;
            __syncthreads();
            cur = nb;
        }
    }

    // D layout: col = l&15, row = (l>>4)*4 + reg (verified). Direct fp16 store.
    u16* dbase = g.dst + (size_t)s * MPAD * g.ldd;
    #pragma unroll
    for (int i = 0; i < 2; ++i) {
        #pragma unroll
        for (int j = 0; j < 2; ++j) {
            int col = n0 + wc * 32 + j * 16 + (l & 15);
            float bv = (s == 0) ? g.bias[col] : 0.f;
            #pragma unroll
            for (int rr = 0; rr < 4; ++rr) {
                int m = m0 + wr * 32 + i * 16 + (l >> 4) * 4 + rr;
                dbase[(size_t)m * g.ldd + col] = f2h(acc[i][j][rr] + bv);
            }
        }
    }
}

// ------------------------------------------------- GEMM -> f32 out --------
// BM=32, BN=32, BK=64. A: fp16 [MPAD][lda]. BT: fp16 [N][K]. Direct f32 store.
// 4 waves as 2x2 of 16x16. ntiles = N/32.
struct GDo {
    const u16* A; const u16* BT; const float* bias; float* dst;
    int lda, ldd, K, N, mstore, ntiles;
};
struct GPo { GDo d[2]; int blk0[3]; int nd; };

__global__ __launch_bounds__(256) void gemm_out(GPo P)
{
    __shared__ u16 sA[2][32][72];
    __shared__ u16 sB[2][32][72];
    int bid = blockIdx.x, gi = 0;
    while (gi + 1 < P.nd && bid >= P.blk0[gi + 1]) ++gi;
    const GDo g = P.d[gi];
    int local = bid - P.blk0[gi];
    const int mt = local / g.ntiles, nt = local % g.ntiles;
    const int m0 = mt * 32, n0 = nt * 32;

    const int t = threadIdx.x;
    const int l = t & 63, w = t >> 6, wr = w >> 1, wc = w & 1;
    const int rowS = t >> 3, kcS = (t & 7) << 3;   // 32 rows x 8 el (A and B)

    f32x4 acc;
    { f32x4 z = {0.f,0.f,0.f,0.f}; acc = z; }

    const u16* ap = g.A  + (size_t)(m0 + rowS) * g.lda + kcS;
    const u16* bp = g.BT + (size_t)(n0 + rowS) * g.K   + kcS;
    uint4 ra = *(const uint4*)ap;
    uint4 rb = *(const uint4*)bp;
    *(uint4*)&sA[0][rowS][kcS] = ra;
    *(uint4*)&sB[0][rowS][kcS] = rb;
    __syncthreads();

    int cur = 0;
    for (int k0 = 0; k0 < g.K; k0 += 64) {
        const bool nxt = (k0 + 64 < g.K);
        if (nxt) {
            ra = *(const uint4*)(ap + k0 + 64);
            rb = *(const uint4*)(bp + k0 + 64);
        }
        #pragma unroll
        for (int ks = 0; ks < 64; ks += 32) {
            const int koff = ks + (l >> 4) * 8;
            half8 af = *(const half8*)&sA[cur][wr * 16 + (l & 15)][koff];
            half8 bf = *(const half8*)&sB[cur][wc * 16 + (l & 15)][koff];
            acc = __builtin_amdgcn_mfma_f32_16x16x32_f16(af, bf, acc, 0, 0, 0);
        }
        if (nxt) {
            int nb = cur ^ 1;
            *(uint4*)&sA[nb][rowS][kcS] = ra;
            *(uint4*)&sB[nb][rowS][kcS] = rb;
            __syncthreads();
            cur = nb;
        }
    }

    {
        int col = n0 + wc * 16 + (l & 15);
        float bv = g.bias[col];
        #pragma unroll
        for (int rr = 0; rr < 4; ++rr) {
            int m = m0 + wr * 16 + (l >> 4) * 4 + rr;
            if (m < g.mstore)
                g.dst[(size_t)m * g.ldd + col] = acc[rr] + bv;
        }
    }
}

// ---------------------------------------------------------------- prep ----
struct TD { const float* src; u16* dst; int K, N, ld, koff, blk0; };
struct PrepP {
    const float *fm0, *fm1, *kp, *ms0, *ms1;
    const float *wg0, *bg0, *wg1, *bg1;
    const float *b2_1, *bo_1, *b2_0, *bo_0;
    u16 *A1h_0, *A1h_1;      // fp16 [MPAD][2C] (GEMM A)
    float *gout0, *gout1;    // [MROW+NKPT][8] sigmoid gates
    float *bsum1, *bsum0;    // b2+bo per level
    TD td[8];
};

// 8 heads x 32 lanes: gate_h = sigmoid(sx . wg[:,h] + bg[h])
__device__ void gates_from_sx(const float* sx, int C, const float* wg,
                              const float* bg, float* gout8)
{
    int t = threadIdx.x;
    int h = t >> 5, e = t & 31;
    float a = 0.f;
    for (int c = e; c < C; c += 32) a += sx[c] * wg[c * 8 + h];
    a += __shfl_xor(a, 16, 32); a += __shfl_xor(a, 8, 32);
    a += __shfl_xor(a, 4, 32);  a += __shfl_xor(a, 2, 32);
    a += __shfl_xor(a, 1, 32);
    if (e == 0) gout8[h] = 1.0f / (1.0f + expf(-(a + bg[h])));
}

// Coalesced pool: 32-lane group per channel; lanes 0..24 = window elements.
// fm reads are stream-once (339 MB footprint > L3): non-temporal.
template<int C, int H, int W>
__device__ void pool_row(int b, int n, const float* fm, const float* kp,
                         const float* ms, u16* A1h, const float* wg,
                         const float* bg, float* gout, float* sx)
{
    const int t = threadIdx.x;   // 256
    const int e = t & 31, grp = t >> 5;   // 8 channel-groups
    float kx = kp[(b * NKPT + n) * 2 + 0];
    float ky = kp[(b * NKPT + n) * 2 + 1];
    int cx = (int)rintf(kx * ((float)W / 192.0f));   // RNE == jnp.round
    int cy = (int)rintf(ky * ((float)H / 256.0f));
    int dy = e / 5, dx = e % 5;
    float wgt = 0.f; int off = 0;
    if (e < 25) {
        int iy = min(max(cy + dy - 2, 0), H - 1);
        int ix = min(max(cx + dx - 2, 0), W - 1);
        off = iy * W + ix;
        wgt = expf(-(float)((dy - 2) * (dy - 2) + (dx - 2) * (dx - 2)) / 8.0f);
    }
    float ws_ = wgt;
    ws_ += __shfl_xor(ws_, 16, 32); ws_ += __shfl_xor(ws_, 8, 32);
    ws_ += __shfl_xor(ws_, 4, 32);  ws_ += __shfl_xor(ws_, 2, 32);
    ws_ += __shfl_xor(ws_, 1, 32);
    const float inv = 1.0f / ws_;

    const size_t plane = (size_t)H * W;
    const float* pf = fm + ((size_t)b * C + grp) * plane + off;
    #pragma unroll 4
    for (int c0 = grp; c0 < C; c0 += 8, pf += 8 * plane) {
        float v = 0.f;
        if (e < 25) v = wgt * __builtin_nontemporal_load(pf);
        v += __shfl_xor(v, 16, 32); v += __shfl_xor(v, 8, 32);
        v += __shfl_xor(v, 4, 32);  v += __shfl_xor(v, 2, 32);
        v += __shfl_xor(v, 1, 32);
        if (e == 0) sx[c0] = v * inv;
    }
    __syncthreads();
    u16* rowh = A1h + (size_t)(b * NKPT + n) * (2 * C);
    for (int c = t; c < C; c += 256) {
        rowh[c] = f2h(sx[c]);
        rowh[C + c] = f2h(ms[n * C + c]);
    }
    gates_from_sx(sx, C, wg, bg, gout + (size_t)(b * NKPT + n) * 8);
}

template<int C>
__device__ void meta_row(int n, const float* ms, u16* A1h, const float* wg,
                         const float* bg, float* gout, float* sx)
{
    const int t = threadIdx.x;
    u16* rowh = A1h + (size_t)(MROW + n) * (2 * C);
    for (int c = t; c < C; c += 256) {
        float v = ms[n * C + c];
        sx[c] = v;
        rowh[c] = f2h(v);
        rowh[C + c] = 0;
    }
    __syncthreads();
    gates_from_sx(sx, C, wg, bg, gout + (size_t)(MROW + n) * 8);
}

__device__ void wtrans_tile(const TD& d, int u, float* sT)  // sT: [64][65] f32
{
    const int ntx = d.N >> 6;
    const int tk = u / ntx, tn = u % ntx;
    const int k0 = tk << 6, n0 = tn << 6;
    const int t = threadIdx.x;
    {
        int r = t >> 2, cq = (t & 3) << 4;
        const float* sp = d.src + (size_t)(k0 + r) * d.N + n0 + cq;
        #pragma unroll
        for (int i = 0; i < 4; ++i) {
            float4 v = *(const float4*)(sp + 4 * i);
            sT[r * 65 + cq + 4 * i + 0] = v.x;
            sT[r * 65 + cq + 4 * i + 1] = v.y;
            sT[r * 65 + cq + 4 * i + 2] = v.z;
            sT[r * 65 + cq + 4 * i + 3] = v.w;
        }
    }
    __syncthreads();
    {
        int nn = t >> 2, kq = (t & 3) << 4;
        u16 hv[16] __attribute__((aligned(16)));
        #pragma unroll
        for (int i = 0; i < 16; ++i) hv[i] = f2h(sT[(kq + i) * 65 + nn]);
        u16* dp = d.dst + (size_t)(n0 + nn) * d.ld + d.koff + k0 + kq;
        *reinterpret_cast<uint4*>(dp) = *reinterpret_cast<uint4*>(&hv[0]);
        *reinterpret_cast<uint4*>(dp + 8) = *reinterpret_cast<uint4*>(&hv[8]);
    }
}

__global__ __launch_bounds__(256) void k1_prep(PrepP P)
{
    __shared__ float ps[64 * 65];
    int bid = blockIdx.x;
    if (bid < 1088) {
        if (bid < 544) pool_row<512, 48, 36>(bid / NKPT, bid % NKPT, P.fm1, P.kp, P.ms1, P.A1h_1, P.wg1, P.bg1, P.gout1, ps);
        else { int r = bid - 544; pool_row<256, 96, 72>(r / NKPT, r % NKPT, P.fm0, P.kp, P.ms0, P.A1h_0, P.wg0, P.bg0, P.gout0, ps); }
    } else if (bid < 1122) {
        int u = bid - 1088;
        if (u < NKPT) meta_row<512>(u, P.ms1, P.A1h_1, P.wg1, P.bg1, P.gout1, ps);
        else          meta_row<256>(u - NKPT, P.ms0, P.A1h_0, P.wg0, P.bg0, P.gout0, ps);
    } else if (bid < 1682) {
        int u = bid - 1122, i = 0;
        while (i + 1 < 8 && u >= P.td[i + 1].blk0) ++i;
        wtrans_tile(P.td[i], u - P.td[i].blk0, ps);
    } else {
        int t = threadIdx.x;
        for (int c = t; c < 512; c += 256) P.bsum1[c] = P.b2_1[c] + P.bo_1[c];
        for (int c = t; c < 256; c += 256) P.bsum0[c] = P.b2_0[c] + P.bo_0[c];
    }
}

// ------------------------------------ rowops: LN+relu AND attn per row ----
// hp: [2][MPAD][C] fp16 parts. qkvp: [2][MPAD][3C]. A4: [MPAD][2C] (h16|om).
template<int C>
__device__ void ln_row(int r, const u16* hp, const float* gg, const float* bb,
                       u16* A4row, float* sh)
{
    const size_t PSh = (size_t)MPAD * C;
    const int t = threadIdx.x;
    const int nc = C >> 8;
    float v[2] = {0.f, 0.f};
    float s1 = 0.f, s2 = 0.f;
    for (int i = 0; i < nc; ++i) {
        size_t idx = (size_t)r * C + t + (i << 8);
        float x = h2f(hp[idx]) + h2f(hp[idx + PSh]);
        v[i] = x; s1 += x; s2 += x * x;
    }
    #pragma unroll
    for (int o = 32; o > 0; o >>= 1) { s1 += __shfl_down(s1, o); s2 += __shfl_down(s2, o); }
    int lane = t & 63, wv = t >> 6;
    if (lane == 0) { sh[wv * 2] = s1; sh[wv * 2 + 1] = s2; }
    __syncthreads();
    if (t == 0) {
        float a = 0.f, b = 0.f;
        #pragma unroll
        for (int q = 0; q < 4; ++q) { a += sh[q * 2]; b += sh[q * 2 + 1]; }
        float m = a / (float)C;
        float var = b / (float)C - m * m;
        sh[8] = m; sh[9] = 1.0f / sqrtf(var + 1e-5f);
    }
    __syncthreads();
    float m = sh[8], rs = sh[9];
    for (int i = 0; i < nc; ++i) {
        int c = t + (i << 8);
        float x = (v[i] - m) * rs * gg[c] + bb[c];
        A4row[c] = f2h(fmaxf(x, 0.f));
    }
}

template<int C>
__device__ void attn_row(int r, const u16* qkvp, const float* gout,
                         u16* A4row, float* sred)
{
    constexpr int D = C / 8;
    constexpr int TC = 3 * C;
    const size_t PS = (size_t)MPAD * TC;
    const int t = threadIdx.x;
    const int n = r % NKPT;
    const size_t rb = (size_t)r * TC;
    const size_t mb = (size_t)(MROW + n) * TC;
    {
        int dot = t >> 3, sub = t & 7;           // 32 dots x 8 threads
        int p = dot >> 3, h = dot & 7;
        size_t qb = ((p & 2) ? mb : rb) + h * D + sub * (D / 8);
        size_t kb = ((p & 1) ? mb : rb) + C + h * D + sub * (D / 8);
        float a = 0.f;
        #pragma unroll
        for (int i = 0; i < D / 8; ++i) {
            float qv = h2f(qkvp[qb + i]) + h2f(qkvp[qb + i + PS]);
            float kv = h2f(qkvp[kb + i]) + h2f(qkvp[kb + i + PS]);
            a += qv * kv;
        }
        a += __shfl_xor(a, 4, 8); a += __shfl_xor(a, 2, 8); a += __shfl_xor(a, 1, 8);
        if (sub == 0) sred[dot] = a;
    }
    if (t >= 32 && t < 40) sred[32 + (t - 32)] = gout[(size_t)r * 8 + (t - 32)];
    else if (t >= 40 && t < 48) sred[32 + (t - 32)] = gout[(size_t)(MROW + n) * 8 + (t - 40)];
    __syncthreads();
    if (t < 8) {
        int h = t;
        float scale = (float)(1.0 / sqrt((double)D));
        float c0 = 0.f, c1 = 0.f;
        #pragma unroll
        for (int s = 0; s < 2; ++s) {
            float a0 = sred[(2 * s) * 8 + h] * scale;
            float a1 = sred[(2 * s + 1) * 8 + h] * scale;
            float mx = fmaxf(a0, a1);
            float e0 = expf(a0 - mx), e1 = expf(a1 - mx);
            float inv = 1.0f / (e0 + e1);
            float gt = sred[32 + s * 8 + h];
            c0 += e0 * inv * gt;
            c1 += e1 * inv * gt;
        }
        sred[48 + h] = 0.5f * c0;
        sred[56 + h] = 0.5f * c1;
    }
    __syncthreads();
    for (int c = t; c < C; c += 256) {
        int h = c / D;
        float v0 = h2f(qkvp[rb + 2 * C + c]) + h2f(qkvp[rb + 2 * C + c + PS]);
        float v1 = h2f(qkvp[mb + 2 * C + c]) + h2f(qkvp[mb + 2 * C + c + PS]);
        A4row[C + c] = f2h(sred[48 + h] * v0 + sred[56 + h] * v1);
    }
}

struct RP {
    const u16 *hp1, *hp0;
    u16 *A4_1, *A4_0;
    const float *g1, *be1, *g0, *be0;
    const u16 *qkvp1, *qkvp0;
    const float *gout1, *gout0;
};
__global__ __launch_bounds__(256) void k3_rowops(RP P)
{
    __shared__ float sh[64];
    int bid = blockIdx.x;
    int lvl1 = bid < 544;
    int r = lvl1 ? bid : bid - 544;
    if (lvl1) {
        u16* A4row = P.A4_1 + (size_t)r * 1024;
        ln_row<512>(r, P.hp1, P.g1, P.be1, A4row, sh);
        __syncthreads();   // sh reused as sred
        attn_row<512>(r, P.qkvp1, P.gout1, A4row, sh);
    } else {
        u16* A4row = P.A4_0 + (size_t)r * 512;
        ln_row<256>(r, P.hp0, P.g0, P.be0, A4row, sh);
        __syncthreads();
        attn_row<256>(r, P.qkvp0, P.gout0, A4row, sh);
    }
}

// --------------------------------------------- fallback (round-2 kernel) --
template<int C, int H, int W>
__global__ __launch_bounds__(C) void fb_level(
    const float* __restrict__ fm, const float* __restrict__ kp,
    const float* __restrict__ ms, const float* __restrict__ w1,
    const float* __restrict__ b1, const float* __restrict__ gvec,
    const float* __restrict__ beta, const float* __restrict__ w2,
    const float* __restrict__ b2, const float* __restrict__ wqkv,
    const float* __restrict__ bqkv, const float* __restrict__ wg,
    const float* __restrict__ bg, const float* __restrict__ wo,
    const float* __restrict__ bo, float* __restrict__ out)
{
    constexpr int D = C / 8;
    constexpr int NW = C / 64;
    __shared__ float x0[C], x1[C], hbuf[C];
    __shared__ float q0[C], k0[C], v0[C], q1[C], k1[C], v1[C];
    __shared__ float om[C];
    __shared__ float gw[25];
    __shared__ float gwsum_inv;
    __shared__ float redA[NW], redB[NW];
    __shared__ float stats[2];
    __shared__ float gates[2][8];
    __shared__ float att[2][2][8];
    const int j = threadIdx.x;
    const int blk = blockIdx.x;
    const int b = blk / NKPT, n = blk % NKPT;
    if (j < 25) { int dy = j / 5 - 2, dx = j % 5 - 2; gw[j] = expf(-(float)(dy*dy+dx*dx) / 8.0f); }
    __syncthreads();
    if (j == 0) { float s = 0.f; for (int t2 = 0; t2 < 25; ++t2) s += gw[t2]; gwsum_inv = 1.0f / s; }
    float kx = kp[(b * NKPT + n) * 2 + 0];
    float ky = kp[(b * NKPT + n) * 2 + 1];
    int cx = (int)rintf(kx * ((float)W / 192.0f));
    int cy = (int)rintf(ky * ((float)H / 256.0f));
    int ix[5], iy[5];
    #pragma unroll
    for (int t2 = 0; t2 < 5; ++t2) {
        ix[t2] = min(max(cx + t2 - 2, 0), W - 1);
        iy[t2] = min(max(cy + t2 - 2, 0), H - 1);
    }
    __syncthreads();
    {
        const float* fmb = fm + ((size_t)b * C + j) * (H * W);
        float acc = 0.f;
        #pragma unroll
        for (int yy = 0; yy < 5; ++yy) {
            const float* row = fmb + iy[yy] * W;
            #pragma unroll
            for (int xx = 0; xx < 5; ++xx) acc += gw[yy * 5 + xx] * row[ix[xx]];
        }
        x0[j] = acc * gwsum_inv;
        x1[j] = ms[n * C + j];
    }
    __syncthreads();
    float hacc = b1[j];
    for (int i = 0; i < C; ++i) hacc += x0[i] * w1[i * C + j];
    for (int i = 0; i < C; ++i) hacc += x1[i] * w1[(C + i) * C + j];
    {
        float s1 = hacc, s2 = hacc * hacc;
        #pragma unroll
        for (int o = 32; o > 0; o >>= 1) { s1 += __shfl_down(s1, o); s2 += __shfl_down(s2, o); }
        int lane = j & 63, wid = j >> 6;
        if (lane == 0) { redA[wid] = s1; redB[wid] = s2; }
        __syncthreads();
        if (j == 0) {
            float t1 = 0.f, t2 = 0.f;
            for (int w = 0; w < NW; ++w) { t1 += redA[w]; t2 += redB[w]; }
            float m = t1 / (float)C, v = t2 / (float)C - m * m;
            stats[0] = m; stats[1] = 1.0f / sqrtf(v + 1e-5f);
        }
        __syncthreads();
    }
    hbuf[j] = fmaxf((hacc - stats[0]) * stats[1] * gvec[j] + beta[j], 0.f);
    __syncthreads();
    float pj = b2[j];
    for (int i = 0; i < C; ++i) pj += hbuf[i] * w2[i * C + j];
    {
        float aq0 = bqkv[j], ak0 = bqkv[C + j], av0 = bqkv[2 * C + j];
        float aq1 = aq0, ak1 = ak0, av1 = av0;
        for (int i = 0; i < C; ++i) {
            float xi0 = x0[i], xi1 = x1[i];
            const float* wr = wqkv + (size_t)i * (3 * C);
            float wq = wr[j], wk = wr[C + j], wv = wr[2 * C + j];
            aq0 += xi0 * wq; aq1 += xi1 * wq;
            ak0 += xi0 * wk; ak1 += xi1 * wk;
            av0 += xi0 * wv; av1 += xi1 * wv;
        }
        q0[j] = aq0; k0[j] = ak0; v0[j] = av0;
        q1[j] = aq1; k1[j] = ak1; v1[j] = av1;
    }
    __syncthreads();
    if (j < 16) {
        int s = j >> 3, hh = j & 7;
        const float* xs = s ? x1 : x0;
        float a = bg[hh];
        for (int i = 0; i < C; ++i) a += xs[i] * wg[i * 8 + hh];
        gates[s][hh] = 1.0f / (1.0f + expf(-a));
    }
    if (j < 32) {
        int hh = j >> 2, st = j & 3;
        const float* qs = (st & 2) ? q1 : q0;
        const float* kt = (st & 1) ? k1 : k0;
        float a = 0.f;
        for (int i = hh * D; i < (hh + 1) * D; ++i) a += qs[i] * kt[i];
        att[(st >> 1)][st & 1][hh] = a;
    }
    __syncthreads();
    if (j < 16) {
        int s = j >> 3, hh = j & 7;
        const float inv = 1.0f / sqrtf((float)D);
        float a0 = att[s][0][hh] * inv, a1 = att[s][1][hh] * inv;
        float mx = fmaxf(a0, a1);
        float e0 = expf(a0 - mx), e1 = expf(a1 - mx);
        float den = e0 + e1;
        att[s][0][hh] = e0 / den; att[s][1][hh] = e1 / den;
    }
    __syncthreads();
    {
        int hh = j / D;
        float o0 = (att[0][0][hh] * v0[j] + att[0][1][hh] * v1[j]) * gates[0][hh];
        float o1 = (att[1][0][hh] * v0[j] + att[1][1][hh] * v1[j]) * gates[1][hh];
        om[j] = 0.5f * (o0 + o1);
    }
    __syncthreads();
    float oacc = bo[j];
    for (int i = 0; i < C; ++i) oacc += om[i] * wo[i * C + j];
    out[((size_t)b * NKPT + n) * C + j] = oacc + pj;
}

// ------------------------------------------------------------- launch -----
extern "C" void kernel_launch(void* const* d_in, const int* in_sizes, int n_in,
                              void* d_out, int out_size, void* d_ws, size_t ws_size,
                              hipStream_t stream) {
    (void)in_sizes; (void)n_in; (void)out_size;
    const float* fm0  = (const float*)d_in[0];
    const float* fm1  = (const float*)d_in[1];
    const float* kp   = (const float*)d_in[2];
    const float* ms0     = (const float*)d_in[3];
    const float* p0_w1   = (const float*)d_in[4];
    const float* p0_b1   = (const float*)d_in[5];
    const float* p0_g    = (const float*)d_in[6];
    const float* p0_beta = (const float*)d_in[7];
    const float* p0_w2   = (const float*)d_in[8];
    const float* p0_b2   = (const float*)d_in[9];
    const float* a0_wqkv = (const float*)d_in[10];
    const float* a0_bqkv = (const float*)d_in[11];
    const float* a0_wg   = (const float*)d_in[12];
    const float* a0_bg   = (const float*)d_in[13];
    const float* a0_wo   = (const float*)d_in[14];
    const float* a0_bo   = (const float*)d_in[15];
    const float* ms1     = (const float*)d_in[16];
    const float* p1_w1   = (const float*)d_in[17];
    const float* p1_b1   = (const float*)d_in[18];
    const float* p1_g    = (const float*)d_in[19];
    const float* p1_beta = (const float*)d_in[20];
    const float* p1_w2   = (const float*)d_in[21];
    const float* p1_b2   = (const float*)d_in[22];
    const float* a1_wqkv = (const float*)d_in[23];
    const float* a1_bqkv = (const float*)d_in[24];
    const float* a1_wg   = (const float*)d_in[25];
    const float* a1_bg   = (const float*)d_in[26];
    const float* a1_wo   = (const float*)d_in[27];
    const float* a1_bo   = (const float*)d_in[28];

    float* out0 = (float*)d_out;                               // (544,256)
    float* out1 = (float*)d_out + (size_t)MROW * 256;          // (544,512)

    const size_t WS_NEED = 15400000;
    if (ws_size < WS_NEED || d_ws == nullptr) {
        fb_level<256, 96, 72><<<MROW, 256, 0, stream>>>(
            fm0, kp, ms0, p0_w1, p0_b1, p0_g, p0_beta, p0_w2, p0_b2,
            a0_wqkv, a0_bqkv, a0_wg, a0_bg, a0_wo, a0_bo, out0);
        fb_level<512, 48, 36><<<MROW, 512, 0, stream>>>(
            fm1, kp, ms1, p1_w1, p1_b1, p1_g, p1_beta, p1_w2, p1_b2,
            a1_wqkv, a1_bqkv, a1_wg, a1_bg, a1_wo, a1_bo, out1);
        return;
    }

    char* cur = (char*)d_ws;
    auto alloc = [&](size_t bytes) { char* p = cur; cur += (bytes + 255) & ~(size_t)255; return p; };
    u16* A1h_1 = (u16*)alloc((size_t)MPAD * 1024 * 2);
    u16* A1h_0 = (u16*)alloc((size_t)MPAD * 512 * 2);
    u16* hp_1  = (u16*)alloc((size_t)2 * MPAD * 512 * 2);   // [2][MPAD][512]
    u16* hp_0  = (u16*)alloc((size_t)2 * MPAD * 256 * 2);
    u16* qkvp_1 = (u16*)alloc((size_t)2 * MPAD * 1536 * 2); // [2][MPAD][1536]
    u16* qkvp_0 = (u16*)alloc((size_t)2 * MPAD * 768 * 2);
    u16* A4_1  = (u16*)alloc((size_t)MPAD * 1024 * 2);      // [MPAD][h16|om]
    u16* A4_0  = (u16*)alloc((size_t)MPAD * 512 * 2);
    u16* w1T_1   = (u16*)alloc((size_t)512 * 1024 * 2);
    u16* wqkvT_1 = (u16*)alloc((size_t)1536 * 512 * 2);
    u16* w24T_1  = (u16*)alloc((size_t)512 * 1024 * 2);     // [512][w2T|woT]
    u16* w1T_0   = (u16*)alloc((size_t)256 * 512 * 2);
    u16* wqkvT_0 = (u16*)alloc((size_t)768 * 256 * 2);
    u16* w24T_0  = (u16*)alloc((size_t)256 * 512 * 2);
    float* gout1 = (float*)alloc((size_t)(MROW + NKPT) * 8 * 4);
    float* gout0 = (float*)alloc((size_t)(MROW + NKPT) * 8 * 4);
    float* bsum1 = (float*)alloc(512 * 4);
    float* bsum0 = (float*)alloc(256 * 4);

    // ---- K1: pool(+gates) + meta + weight transpose/pack + bias-sum ----
    PrepP pp;
    pp.fm0 = fm0; pp.fm1 = fm1; pp.kp = kp; pp.ms0 = ms0; pp.ms1 = ms1;
    pp.wg0 = a0_wg; pp.bg0 = a0_bg; pp.wg1 = a1_wg; pp.bg1 = a1_bg;
    pp.b2_1 = p1_b2; pp.bo_1 = a1_bo; pp.b2_0 = p0_b2; pp.bo_0 = a0_bo;
    pp.A1h_0 = A1h_0; pp.A1h_1 = A1h_1;
    pp.gout0 = gout0; pp.gout1 = gout1;
    pp.bsum1 = bsum1; pp.bsum0 = bsum0;
    int tcum = 0;
    auto setTD = [&](int i, const float* src, u16* dst, int K, int N, int ld, int koff) {
        pp.td[i].src = src; pp.td[i].dst = dst; pp.td[i].K = K; pp.td[i].N = N;
        pp.td[i].ld = ld; pp.td[i].koff = koff;
        pp.td[i].blk0 = tcum; tcum += (K / 64) * (N / 64);
    };
    setTD(0, p1_w1,   w1T_1,   1024, 512,  1024, 0);
    setTD(1, a1_wqkv, wqkvT_1, 512,  1536, 512,  0);
    setTD(2, p1_w2,   w24T_1,  512,  512,  1024, 0);
    setTD(3, a1_wo,   w24T_1,  512,  512,  1024, 512);
    setTD(4, p0_w1,   w1T_0,   512,  256,  512,  0);
    setTD(5, a0_wqkv, wqkvT_0, 256,  768,  256,  0);
    setTD(6, p0_w2,   w24T_0,  256,  256,  512,  0);
    setTD(7, a0_wo,   w24T_0,  256,  256,  512,  256);
    k1_prep<<<1683, 256, 0, stream>>>(pp);   // 1088 + 34 + 560 + 1

    // ---- K2: w1 + wqkv GEMMs, split-K=2 -> fp16 part buffers (no atomics) --
    GPp g2; g2.nd = 4;
    g2.d[0] = { A1h_1, w1T_1,   p1_b1,   hp_1,   1024, 512,  1024, 512,  8,  2 };
    g2.d[1] = { A1h_1, wqkvT_1, a1_bqkv, qkvp_1, 1024, 1536, 512,  1536, 24, 2 };
    g2.d[2] = { A1h_0, w1T_0,   p0_b1,   hp_0,   512,  256,  512,  256,  4,  2 };
    g2.d[3] = { A1h_0, wqkvT_0, a0_bqkv, qkvp_0, 512,  768,  256,  768,  12, 2 };
    g2.blk0[0] = 0;
    for (int i = 0; i < 4; ++i) g2.blk0[i + 1] = g2.blk0[i] + 9 * g2.d[i].ntiles * g2.d[i].sk;
    gemm_part<<<g2.blk0[4], 256, 0, stream>>>(g2);

    // ---- K3: per-row LN+relu AND attention -> A4 (1088 blocks) ----
    RP rp;
    rp.hp1 = hp_1; rp.hp0 = hp_0; rp.A4_1 = A4_1; rp.A4_0 = A4_0;
    rp.g1 = p1_g; rp.be1 = p1_beta; rp.g0 = p0_g; rp.be0 = p0_beta;
    rp.qkvp1 = qkvp_1; rp.qkvp0 = qkvp_0;
    rp.gout1 = gout1; rp.gout0 = gout0;
    k3_rowops<<<1088, 256, 0, stream>>>(rp);

    // ---- K4: out = [h16|om] @ [w2T|woT]^T + (b2+bo), BN=32, direct store ----
    GPo g4; g4.nd = 2;
    g4.d[0] = { A4_1, w24T_1, bsum1, out1, 1024, 512, 1024, 512, MROW, 16 };
    g4.d[1] = { A4_0, w24T_0, bsum0, out0, 512,  256, 512,  256, MROW, 8 };
    g4.blk0[0] = 0;
    for (int i = 0; i < 2; ++i) g4.blk0[i + 1] = g4.blk0[i] + 18 * g4.d[i].ntiles;
    gemm_out<<<g4.blk0[2], 256, 0, stream>>>(g4);
}

// Round 10
// 81.936 us; speedup vs baseline: 1.2003x; 1.2003x over previous
//
#include <hip/hip_runtime.h>
#include <math.h>

#define NKPT 17
#define BATCH 32
#define MROW 544          // BATCH*NKPT
#define MPAD 576          // 9*64

typedef unsigned short u16;
typedef _Float16 half8 __attribute__((ext_vector_type(8)));
typedef float f32x4 __attribute__((ext_vector_type(4)));

__device__ __forceinline__ u16 f2h(float f) {
    _Float16 h = (_Float16)f;
    u16 u; __builtin_memcpy(&u, &h, 2); return u;
}
__device__ __forceinline__ float h2f(u16 u) {
    _Float16 h; __builtin_memcpy(&h, &u, 2); return (float)h;
}

// ------------------------------------------------- GEMM -> fp16 parts -----
// BM=64, BN=64, BK=64, 256 threads (4 waves as 2x2 of 32x32), double-buffered
// LDS, one barrier per k-step. A: fp16 [MPAD][lda]. BT: fp16 [N][K].
// Split-K: part s stores DIRECTLY (fp16) to dst + s*MPAD*ldd. No atomics.
struct GDp {
    const u16* A; const u16* BT; const float* bias; u16* dst;
    int lda, ldd, K, N, ntiles, sk;
};
struct GPp { GDp d[4]; int blk0[5]; int nd; };

__global__ __launch_bounds__(256) void gemm_part(GPp P)
{
    __shared__ u16 sA[2][64][72];
    __shared__ u16 sB[2][64][72];
    int bid = blockIdx.x, gi = 0;
    while (gi + 1 < P.nd && bid >= P.blk0[gi + 1]) ++gi;
    const GDp g = P.d[gi];
    int local = bid - P.blk0[gi];
    const int nspan = g.ntiles * g.sk;
    const int mt = local / nspan;
    int rem = local - mt * nspan;
    const int nt = rem / g.sk;
    const int s  = rem - nt * g.sk;
    const int m0 = mt * 64, n0 = nt * 64;
    const int Kseg = g.K / g.sk;
    const int kbase = s * Kseg;

    const int t = threadIdx.x;
    const int l = t & 63, w = t >> 6, wr = w >> 1, wc = w & 1;
    const int row = t >> 2, kc = (t & 3) << 4;

    f32x4 acc[2][2];
    #pragma unroll
    for (int i = 0; i < 2; ++i)
        #pragma unroll
        for (int j = 0; j < 2; ++j) { f32x4 z = {0.f,0.f,0.f,0.f}; acc[i][j] = z; }

    const u16* ap = g.A  + (size_t)(m0 + row) * g.lda + kbase + kc;
    const u16* bp = g.BT + (size_t)(n0 + row) * g.K   + kbase + kc;
    uint4 ra0 = *(const uint4*)ap, ra1 = *(const uint4*)(ap + 8);
    uint4 rb0 = *(const uint4*)bp, rb1 = *(const uint4*)(bp + 8);
    *(uint4*)&sA[0][row][kc] = ra0; *(uint4*)&sA[0][row][kc + 8] = ra1;
    *(uint4*)&sB[0][row][kc] = rb0; *(uint4*)&sB[0][row][kc + 8] = rb1;
    __syncthreads();

    int cur = 0;
    for (int k0 = 0; k0 < Kseg; k0 += 64) {
        const bool nxt = (k0 + 64 < Kseg);
        if (nxt) {
            ra0 = *(const uint4*)(ap + k0 + 64); ra1 = *(const uint4*)(ap + k0 + 72);
            rb0 = *(const uint4*)(bp + k0 + 64); rb1 = *(const uint4*)(bp + k0 + 72);
        }
        #pragma unroll
        for (int ks = 0; ks < 64; ks += 32) {
            const int koff = ks + (l >> 4) * 8;
            half8 af0 = *(const half8*)&sA[cur][wr * 32 +      (l & 15)][koff];
            half8 af1 = *(const half8*)&sA[cur][wr * 32 + 16 + (l & 15)][koff];
            half8 bf0 = *(const half8*)&sB[cur][wc * 32 +      (l & 15)][koff];
            half8 bf1 = *(const half8*)&sB[cur][wc * 32 + 16 + (l & 15)][koff];
            acc[0][0] = __builtin_amdgcn_mfma_f32_16x16x32_f16(af0, bf0, acc[0][0], 0, 0, 0);
            acc[0][1] = __builtin_amdgcn_mfma_f32_16x16x32_f16(af0, bf1, acc[0][1], 0, 0, 0);
            acc[1][0] = __builtin_amdgcn_mfma_f32_16x16x32_f16(af1, bf0, acc[1][0], 0, 0, 0);
            acc[1][1] = __builtin_amdgcn_mfma_f32_16x16x32_f16(af1, bf1, acc[1][1], 0, 0, 0);
        }
        if (nxt) {
            int nb = cur ^ 1;
            *(uint4*)&sA[nb][row][kc] = ra0; *(uint4*)&sA[nb][row][kc + 8] = ra1;
            *(uint4*)&sB[nb][row][kc] = rb0; *(uint4*)&sB[nb][row][kc + 8] = rb1;
            __syncthreads();
            cur = nb;
        }
    }

    // D layout: col = l&15, row = (l>>4)*4 + reg (verified). Direct fp16 store.
    u16* dbase = g.dst + (size_t)s * MPAD * g.ldd;
    #pragma unroll
    for (int i = 0; i < 2; ++i) {
        #pragma unroll
        for (int j = 0; j < 2; ++j) {
            int col = n0 + wc * 32 + j * 16 + (l & 15);
            float bv = (s == 0) ? g.bias[col] : 0.f;
            #pragma unroll
            for (int rr = 0; rr < 4; ++rr) {
                int m = m0 + wr * 32 + i * 16 + (l >> 4) * 4 + rr;
                dbase[(size_t)m * g.ldd + col] = f2h(acc[i][j][rr] + bv);
            }
        }
    }
}

// ------------------------------------------------- GEMM -> f32 out --------
// BM=32, BN=64, BK=64. A: fp16 [MPAD][K]. BT: fp16 [N][K]. Direct f32 store.
struct GDo {
    const u16* A; const u16* BT; const float* bias; float* dst;
    int lda, ldd, K, N, mstore, ntiles;
};
struct GPo { GDo d[2]; int blk0[3]; int nd; };

__global__ __launch_bounds__(256) void gemm_out(GPo P)
{
    __shared__ u16 sA[2][32][72];
    __shared__ u16 sB[2][64][72];
    int bid = blockIdx.x, gi = 0;
    while (gi + 1 < P.nd && bid >= P.blk0[gi + 1]) ++gi;
    const GDo g = P.d[gi];
    int local = bid - P.blk0[gi];
    const int mt = local / g.ntiles, nt = local % g.ntiles;
    const int m0 = mt * 32, n0 = nt * 64;

    const int t = threadIdx.x;
    const int l = t & 63, w = t >> 6, wr = w >> 1, wc = w & 1;
    const int rowA = t >> 3, kcA = (t & 7) << 3;   // 32 rows x 8 el
    const int rowB = t >> 2, kcB = (t & 3) << 4;   // 64 rows x 16 el

    f32x4 acc[2];
    { f32x4 z = {0.f,0.f,0.f,0.f}; acc[0] = z; acc[1] = z; }

    const u16* ap = g.A  + (size_t)(m0 + rowA) * g.lda + kcA;
    const u16* bp = g.BT + (size_t)(n0 + rowB) * g.K   + kcB;
    uint4 ra  = *(const uint4*)ap;
    uint4 rb0 = *(const uint4*)bp, rb1 = *(const uint4*)(bp + 8);
    *(uint4*)&sA[0][rowA][kcA] = ra;
    *(uint4*)&sB[0][rowB][kcB] = rb0; *(uint4*)&sB[0][rowB][kcB + 8] = rb1;
    __syncthreads();

    int cur = 0;
    for (int k0 = 0; k0 < g.K; k0 += 64) {
        const bool nxt = (k0 + 64 < g.K);
        if (nxt) {
            ra  = *(const uint4*)(ap + k0 + 64);
            rb0 = *(const uint4*)(bp + k0 + 64); rb1 = *(const uint4*)(bp + k0 + 72);
        }
        #pragma unroll
        for (int ks = 0; ks < 64; ks += 32) {
            const int koff = ks + (l >> 4) * 8;
            half8 af  = *(const half8*)&sA[cur][wr * 16 + (l & 15)][koff];
            half8 bf0 = *(const half8*)&sB[cur][wc * 32 +      (l & 15)][koff];
            half8 bf1 = *(const half8*)&sB[cur][wc * 32 + 16 + (l & 15)][koff];
            acc[0] = __builtin_amdgcn_mfma_f32_16x16x32_f16(af, bf0, acc[0], 0, 0, 0);
            acc[1] = __builtin_amdgcn_mfma_f32_16x16x32_f16(af, bf1, acc[1], 0, 0, 0);
        }
        if (nxt) {
            int nb = cur ^ 1;
            *(uint4*)&sA[nb][rowA][kcA] = ra;
            *(uint4*)&sB[nb][rowB][kcB] = rb0; *(uint4*)&sB[nb][rowB][kcB + 8] = rb1;
            __syncthreads();
            cur = nb;
        }
    }

    #pragma unroll
    for (int j = 0; j < 2; ++j) {
        int col = n0 + wc * 32 + j * 16 + (l & 15);
        float bv = g.bias[col];
        #pragma unroll
        for (int rr = 0; rr < 4; ++rr) {
            int m = m0 + wr * 16 + (l >> 4) * 4 + rr;
            if (m < g.mstore)
                g.dst[(size_t)m * g.ldd + col] = acc[j][rr] + bv;
        }
    }
}

// ---------------------------------------------------------------- prep ----
struct TD { const float* src; u16* dst; int K, N, ld, koff, blk0; };
struct PrepP {
    const float *fm0, *fm1, *kp, *ms0, *ms1;
    const float *wg0, *bg0, *wg1, *bg1;
    const float *b2_1, *bo_1, *b2_0, *bo_0;
    u16 *A1h_0, *A1h_1;      // fp16 [MPAD][2C] (GEMM A)
    float *gout0, *gout1;    // [MROW+NKPT][8] sigmoid gates
    float *bsum1, *bsum0;    // b2+bo per level
    TD td[8];
};

// 8 heads x 32 lanes: gate_h = sigmoid(sx . wg[:,h] + bg[h])
__device__ void gates_from_sx(const float* sx, int C, const float* wg,
                              const float* bg, float* gout8)
{
    int t = threadIdx.x;
    int h = t >> 5, e = t & 31;
    float a = 0.f;
    for (int c = e; c < C; c += 32) a += sx[c] * wg[c * 8 + h];
    a += __shfl_xor(a, 16, 32); a += __shfl_xor(a, 8, 32);
    a += __shfl_xor(a, 4, 32);  a += __shfl_xor(a, 2, 32);
    a += __shfl_xor(a, 1, 32);
    if (e == 0) gout8[h] = 1.0f / (1.0f + expf(-(a + bg[h])));
}

// Coalesced pool: 32-lane group per channel; lanes 0..24 = window elements.
template<int C, int H, int W>
__device__ void pool_row(int b, int n, const float* fm, const float* kp,
                         const float* ms, u16* A1h, const float* wg,
                         const float* bg, float* gout, float* sx)
{
    const int t = threadIdx.x;   // 256
    const int e = t & 31, grp = t >> 5;   // 8 channel-groups
    float kx = kp[(b * NKPT + n) * 2 + 0];
    float ky = kp[(b * NKPT + n) * 2 + 1];
    int cx = (int)rintf(kx * ((float)W / 192.0f));   // RNE == jnp.round
    int cy = (int)rintf(ky * ((float)H / 256.0f));
    int dy = e / 5, dx = e % 5;
    float wgt = 0.f; int off = 0;
    if (e < 25) {
        int iy = min(max(cy + dy - 2, 0), H - 1);
        int ix = min(max(cx + dx - 2, 0), W - 1);
        off = iy * W + ix;
        wgt = expf(-(float)((dy - 2) * (dy - 2) + (dx - 2) * (dx - 2)) / 8.0f);
    }
    float ws_ = wgt;
    ws_ += __shfl_xor(ws_, 16, 32); ws_ += __shfl_xor(ws_, 8, 32);
    ws_ += __shfl_xor(ws_, 4, 32);  ws_ += __shfl_xor(ws_, 2, 32);
    ws_ += __shfl_xor(ws_, 1, 32);
    const float inv = 1.0f / ws_;

    const size_t plane = (size_t)H * W;
    const float* pf = fm + ((size_t)b * C + grp) * plane + off;
    #pragma unroll 4
    for (int c0 = grp; c0 < C; c0 += 8, pf += 8 * plane) {
        float v = 0.f;
        if (e < 25) v = wgt * (*pf);
        v += __shfl_xor(v, 16, 32); v += __shfl_xor(v, 8, 32);
        v += __shfl_xor(v, 4, 32);  v += __shfl_xor(v, 2, 32);
        v += __shfl_xor(v, 1, 32);
        if (e == 0) sx[c0] = v * inv;
    }
    __syncthreads();
    u16* rowh = A1h + (size_t)(b * NKPT + n) * (2 * C);
    for (int c = t; c < C; c += 256) {
        rowh[c] = f2h(sx[c]);
        rowh[C + c] = f2h(ms[n * C + c]);
    }
    gates_from_sx(sx, C, wg, bg, gout + (size_t)(b * NKPT + n) * 8);
}

template<int C>
__device__ void meta_row(int n, const float* ms, u16* A1h, const float* wg,
                         const float* bg, float* gout, float* sx)
{
    const int t = threadIdx.x;
    u16* rowh = A1h + (size_t)(MROW + n) * (2 * C);
    for (int c = t; c < C; c += 256) {
        float v = ms[n * C + c];
        sx[c] = v;
        rowh[c] = f2h(v);
        rowh[C + c] = 0;
    }
    __syncthreads();
    gates_from_sx(sx, C, wg, bg, gout + (size_t)(MROW + n) * 8);
}

__device__ void wtrans_tile(const TD& d, int u, float* sT)  // sT: [64][65] f32
{
    const int ntx = d.N >> 6;
    const int tk = u / ntx, tn = u % ntx;
    const int k0 = tk << 6, n0 = tn << 6;
    const int t = threadIdx.x;
    {
        int r = t >> 2, cq = (t & 3) << 4;
        const float* sp = d.src + (size_t)(k0 + r) * d.N + n0 + cq;
        #pragma unroll
        for (int i = 0; i < 4; ++i) {
            float4 v = *(const float4*)(sp + 4 * i);
            sT[r * 65 + cq + 4 * i + 0] = v.x;
            sT[r * 65 + cq + 4 * i + 1] = v.y;
            sT[r * 65 + cq + 4 * i + 2] = v.z;
            sT[r * 65 + cq + 4 * i + 3] = v.w;
        }
    }
    __syncthreads();
    {
        int nn = t >> 2, kq = (t & 3) << 4;
        u16 hv[16] __attribute__((aligned(16)));
        #pragma unroll
        for (int i = 0; i < 16; ++i) hv[i] = f2h(sT[(kq + i) * 65 + nn]);
        u16* dp = d.dst + (size_t)(n0 + nn) * d.ld + d.koff + k0 + kq;
        *reinterpret_cast<uint4*>(dp) = *reinterpret_cast<uint4*>(&hv[0]);
        *reinterpret_cast<uint4*>(dp + 8) = *reinterpret_cast<uint4*>(&hv[8]);
    }
}

__global__ __launch_bounds__(256) void k1_prep(PrepP P)
{
    __shared__ float ps[64 * 65];
    int bid = blockIdx.x;
    if (bid < 1088) {
        if (bid < 544) pool_row<512, 48, 36>(bid / NKPT, bid % NKPT, P.fm1, P.kp, P.ms1, P.A1h_1, P.wg1, P.bg1, P.gout1, ps);
        else { int r = bid - 544; pool_row<256, 96, 72>(r / NKPT, r % NKPT, P.fm0, P.kp, P.ms0, P.A1h_0, P.wg0, P.bg0, P.gout0, ps); }
    } else if (bid < 1122) {
        int u = bid - 1088;
        if (u < NKPT) meta_row<512>(u, P.ms1, P.A1h_1, P.wg1, P.bg1, P.gout1, ps);
        else          meta_row<256>(u - NKPT, P.ms0, P.A1h_0, P.wg0, P.bg0, P.gout0, ps);
    } else if (bid < 1682) {
        int u = bid - 1122, i = 0;
        while (i + 1 < 8 && u >= P.td[i + 1].blk0) ++i;
        wtrans_tile(P.td[i], u - P.td[i].blk0, ps);
    } else {
        int t = threadIdx.x;
        for (int c = t; c < 512; c += 256) P.bsum1[c] = P.b2_1[c] + P.bo_1[c];
        for (int c = t; c < 256; c += 256) P.bsum0[c] = P.b2_0[c] + P.bo_0[c];
    }
}

// ----------------------------------------------- rowops: LN+relu / attn ---
// hp: [2][MPAD][C] fp16 parts. qkvp: [2][MPAD][3C]. A4: [MPAD][2C] (h16|om).
template<int C>
__device__ void attn_row(int r, const u16* qkvp, const float* gout,
                         u16* A4, float* sred)
{
    constexpr int D = C / 8;
    constexpr int TC = 3 * C;
    const size_t PS = (size_t)MPAD * TC;
    const int t = threadIdx.x;
    const int n = r % NKPT;
    const size_t rb = (size_t)r * TC;
    const size_t mb = (size_t)(MROW + n) * TC;
    {
        int dot = t >> 3, sub = t & 7;           // 32 dots x 8 threads
        int p = dot >> 3, h = dot & 7;
        size_t qb = ((p & 2) ? mb : rb) + h * D + sub * (D / 8);
        size_t kb = ((p & 1) ? mb : rb) + C + h * D + sub * (D / 8);
        float a = 0.f;
        #pragma unroll
        for (int i = 0; i < D / 8; ++i) {
            float qv = h2f(qkvp[qb + i]) + h2f(qkvp[qb + i + PS]);
            float kv = h2f(qkvp[kb + i]) + h2f(qkvp[kb + i + PS]);
            a += qv * kv;
        }
        a += __shfl_xor(a, 4, 8); a += __shfl_xor(a, 2, 8); a += __shfl_xor(a, 1, 8);
        if (sub == 0) sred[dot] = a;
    }
    if (t >= 32 && t < 40) sred[32 + (t - 32)] = gout[(size_t)r * 8 + (t - 32)];
    else if (t >= 40 && t < 48) sred[32 + (t - 32)] = gout[(size_t)(MROW + n) * 8 + (t - 40)];
    __syncthreads();
    if (t < 8) {
        int h = t;
        float scale = (float)(1.0 / sqrt((double)D));
        float c0 = 0.f, c1 = 0.f;
        #pragma unroll
        for (int s = 0; s < 2; ++s) {
            float a0 = sred[(2 * s) * 8 + h] * scale;
            float a1 = sred[(2 * s + 1) * 8 + h] * scale;
            float mx = fmaxf(a0, a1);
            float e0 = expf(a0 - mx), e1 = expf(a1 - mx);
            float inv = 1.0f / (e0 + e1);
            float gt = sred[32 + s * 8 + h];
            c0 += e0 * inv * gt;
            c1 += e1 * inv * gt;
        }
        sred[48 + h] = 0.5f * c0;
        sred[56 + h] = 0.5f * c1;
    }
    __syncthreads();
    for (int c = t; c < C; c += 256) {
        int h = c / D;
        float v0 = h2f(qkvp[rb + 2 * C + c]) + h2f(qkvp[rb + 2 * C + c + PS]);
        float v1 = h2f(qkvp[mb + 2 * C + c]) + h2f(qkvp[mb + 2 * C + c + PS]);
        A4[(size_t)r * (2 * C) + C + c] = f2h(sred[48 + h] * v0 + sred[56 + h] * v1);
    }
}

struct RP {
    const u16 *hp1, *hp0;
    u16 *A4_1, *A4_0;
    const float *g1, *be1, *g0, *be0;
    const u16 *qkvp1, *qkvp0;
    const float *gout1, *gout0;
};
__global__ __launch_bounds__(256) void k3_rowops(RP P)
{
    __shared__ float sh[64];
    int bid = blockIdx.x;
    if (bid < 1088) {
        int lvl1 = bid < 544;
        int r = lvl1 ? bid : bid - 544;
        int C = lvl1 ? 512 : 256;
        const u16* hp = lvl1 ? P.hp1 : P.hp0;
        const size_t PSh = (size_t)MPAD * C;
        u16* A4 = (lvl1 ? P.A4_1 : P.A4_0) + (size_t)r * (2 * C);
        const float* gg = lvl1 ? P.g1 : P.g0;
        const float* bb = lvl1 ? P.be1 : P.be0;
        int t = threadIdx.x;
        int nc = C >> 8;
        float v[2] = {0.f, 0.f};
        float s1 = 0.f, s2 = 0.f;
        for (int i = 0; i < nc; ++i) {
            size_t idx = (size_t)r * C + t + (i << 8);
            float x = h2f(hp[idx]) + h2f(hp[idx + PSh]);
            v[i] = x; s1 += x; s2 += x * x;
        }
        #pragma unroll
        for (int o = 32; o > 0; o >>= 1) { s1 += __shfl_down(s1, o); s2 += __shfl_down(s2, o); }
        int lane = t & 63, wv = t >> 6;
        if (lane == 0) { sh[wv * 2] = s1; sh[wv * 2 + 1] = s2; }
        __syncthreads();
        if (t == 0) {
            float a = 0.f, b = 0.f;
            #pragma unroll
            for (int q = 0; q < 4; ++q) { a += sh[q * 2]; b += sh[q * 2 + 1]; }
            float m = a / (float)C;
            float var = b / (float)C - m * m;
            sh[8] = m; sh[9] = 1.0f / sqrtf(var + 1e-5f);
        }
        __syncthreads();
        float m = sh[8], rs = sh[9];
        for (int i = 0; i < nc; ++i) {
            int c = t + (i << 8);
            float x = (v[i] - m) * rs * gg[c] + bb[c];
            A4[c] = f2h(fmaxf(x, 0.f));
        }
    } else {
        int a = bid - 1088;
        if (a < 544) attn_row<512>(a, P.qkvp1, P.gout1, P.A4_1, sh);
        else         attn_row<256>(a - 544, P.qkvp0, P.gout0, P.A4_0, sh);
    }
}

// --------------------------------------------- fallback (round-2 kernel) --
template<int C, int H, int W>
__global__ __launch_bounds__(C) void fb_level(
    const float* __restrict__ fm, const float* __restrict__ kp,
    const float* __restrict__ ms, const float* __restrict__ w1,
    const float* __restrict__ b1, const float* __restrict__ gvec,
    const float* __restrict__ beta, const float* __restrict__ w2,
    const float* __restrict__ b2, const float* __restrict__ wqkv,
    const float* __restrict__ bqkv, const float* __restrict__ wg,
    const float* __restrict__ bg, const float* __restrict__ wo,
    const float* __restrict__ bo, float* __restrict__ out)
{
    constexpr int D = C / 8;
    constexpr int NW = C / 64;
    __shared__ float x0[C], x1[C], hbuf[C];
    __shared__ float q0[C], k0[C], v0[C], q1[C], k1[C], v1[C];
    __shared__ float om[C];
    __shared__ float gw[25];
    __shared__ float gwsum_inv;
    __shared__ float redA[NW], redB[NW];
    __shared__ float stats[2];
    __shared__ float gates[2][8];
    __shared__ float att[2][2][8];
    const int j = threadIdx.x;
    const int blk = blockIdx.x;
    const int b = blk / NKPT, n = blk % NKPT;
    if (j < 25) { int dy = j / 5 - 2, dx = j % 5 - 2; gw[j] = expf(-(float)(dy*dy+dx*dx) / 8.0f); }
    __syncthreads();
    if (j == 0) { float s = 0.f; for (int t2 = 0; t2 < 25; ++t2) s += gw[t2]; gwsum_inv = 1.0f / s; }
    float kx = kp[(b * NKPT + n) * 2 + 0];
    float ky = kp[(b * NKPT + n) * 2 + 1];
    int cx = (int)rintf(kx * ((float)W / 192.0f));
    int cy = (int)rintf(ky * ((float)H / 256.0f));
    int ix[5], iy[5];
    #pragma unroll
    for (int t2 = 0; t2 < 5; ++t2) {
        ix[t2] = min(max(cx + t2 - 2, 0), W - 1);
        iy[t2] = min(max(cy + t2 - 2, 0), H - 1);
    }
    __syncthreads();
    {
        const float* fmb = fm + ((size_t)b * C + j) * (H * W);
        float acc = 0.f;
        #pragma unroll
        for (int yy = 0; yy < 5; ++yy) {
            const float* row = fmb + iy[yy] * W;
            #pragma unroll
            for (int xx = 0; xx < 5; ++xx) acc += gw[yy * 5 + xx] * row[ix[xx]];
        }
        x0[j] = acc * gwsum_inv;
        x1[j] = ms[n * C + j];
    }
    __syncthreads();
    float hacc = b1[j];
    for (int i = 0; i < C; ++i) hacc += x0[i] * w1[i * C + j];
    for (int i = 0; i < C; ++i) hacc += x1[i] * w1[(C + i) * C + j];
    {
        float s1 = hacc, s2 = hacc * hacc;
        #pragma unroll
        for (int o = 32; o > 0; o >>= 1) { s1 += __shfl_down(s1, o); s2 += __shfl_down(s2, o); }
        int lane = j & 63, wid = j >> 6;
        if (lane == 0) { redA[wid] = s1; redB[wid] = s2; }
        __syncthreads();
        if (j == 0) {
            float t1 = 0.f, t2 = 0.f;
            for (int w = 0; w < NW; ++w) { t1 += redA[w]; t2 += redB[w]; }
            float m = t1 / (float)C, v = t2 / (float)C - m * m;
            stats[0] = m; stats[1] = 1.0f / sqrtf(v + 1e-5f);
        }
        __syncthreads();
    }
    hbuf[j] = fmaxf((hacc - stats[0]) * stats[1] * gvec[j] + beta[j], 0.f);
    __syncthreads();
    float pj = b2[j];
    for (int i = 0; i < C; ++i) pj += hbuf[i] * w2[i * C + j];
    {
        float aq0 = bqkv[j], ak0 = bqkv[C + j], av0 = bqkv[2 * C + j];
        float aq1 = aq0, ak1 = ak0, av1 = av0;
        for (int i = 0; i < C; ++i) {
            float xi0 = x0[i], xi1 = x1[i];
            const float* wr = wqkv + (size_t)i * (3 * C);
            float wq = wr[j], wk = wr[C + j], wv = wr[2 * C + j];
            aq0 += xi0 * wq; aq1 += xi1 * wq;
            ak0 += xi0 * wk; ak1 += xi1 * wk;
            av0 += xi0 * wv; av1 += xi1 * wv;
        }
        q0[j] = aq0; k0[j] = ak0; v0[j] = av0;
        q1[j] = aq1; k1[j] = ak1; v1[j] = av1;
    }
    __syncthreads();
    if (j < 16) {
        int s = j >> 3, hh = j & 7;
        const float* xs = s ? x1 : x0;
        float a = bg[hh];
        for (int i = 0; i < C; ++i) a += xs[i] * wg[i * 8 + hh];
        gates[s][hh] = 1.0f / (1.0f + expf(-a));
    }
    if (j < 32) {
        int hh = j >> 2, st = j & 3;
        const float* qs = (st & 2) ? q1 : q0;
        const float* kt = (st & 1) ? k1 : k0;
        float a = 0.f;
        for (int i = hh * D; i < (hh + 1) * D; ++i) a += qs[i] * kt[i];
        att[(st >> 1)][st & 1][hh] = a;
    }
    __syncthreads();
    if (j < 16) {
        int s = j >> 3, hh = j & 7;
        const float inv = 1.0f / sqrtf((float)D);
        float a0 = att[s][0][hh] * inv, a1 = att[s][1][hh] * inv;
        float mx = fmaxf(a0, a1);
        float e0 = expf(a0 - mx), e1 = expf(a1 - mx);
        float den = e0 + e1;
        att[s][0][hh] = e0 / den; att[s][1][hh] = e1 / den;
    }
    __syncthreads();
    {
        int hh = j / D;
        float o0 = (att[0][0][hh] * v0[j] + att[0][1][hh] * v1[j]) * gates[0][hh];
        float o1 = (att[1][0][hh] * v0[j] + att[1][1][hh] * v1[j]) * gates[1][hh];
        om[j] = 0.5f * (o0 + o1);
    }
    __syncthreads();
    float oacc = bo[j];
    for (int i = 0; i < C; ++i) oacc += om[i] * wo[i * C + j];
    out[((size_t)b * NKPT + n) * C + j] = oacc + pj;
}

// ------------------------------------------------------------- launch -----
extern "C" void kernel_launch(void* const* d_in, const int* in_sizes, int n_in,
                              void* d_out, int out_size, void* d_ws, size_t ws_size,
                              hipStream_t stream) {
    (void)in_sizes; (void)n_in; (void)out_size;
    const float* fm0  = (const float*)d_in[0];
    const float* fm1  = (const float*)d_in[1];
    const float* kp   = (const float*)d_in[2];
    const float* ms0     = (const float*)d_in[3];
    const float* p0_w1   = (const float*)d_in[4];
    const float* p0_b1   = (const float*)d_in[5];
    const float* p0_g    = (const float*)d_in[6];
    const float* p0_beta = (const float*)d_in[7];
    const float* p0_w2   = (const float*)d_in[8];
    const float* p0_b2   = (const float*)d_in[9];
    const float* a0_wqkv = (const float*)d_in[10];
    const float* a0_bqkv = (const float*)d_in[11];
    const float* a0_wg   = (const float*)d_in[12];
    const float* a0_bg   = (const float*)d_in[13];
    const float* a0_wo   = (const float*)d_in[14];
    const float* a0_bo   = (const float*)d_in[15];
    const float* ms1     = (const float*)d_in[16];
    const float* p1_w1   = (const float*)d_in[17];
    const float* p1_b1   = (const float*)d_in[18];
    const float* p1_g    = (const float*)d_in[19];
    const float* p1_beta = (const float*)d_in[20];
    const float* p1_w2   = (const float*)d_in[21];
    const float* p1_b2   = (const float*)d_in[22];
    const float* a1_wqkv = (const float*)d_in[23];
    const float* a1_bqkv = (const float*)d_in[24];
    const float* a1_wg   = (const float*)d_in[25];
    const float* a1_bg   = (const float*)d_in[26];
    const float* a1_wo   = (const float*)d_in[27];
    const float* a1_bo   = (const float*)d_in[28];

    float* out0 = (float*)d_out;                               // (544,256)
    float* out1 = (float*)d_out + (size_t)MROW * 256;          // (544,512)

    const size_t WS_NEED = 15400000;
    if (ws_size < WS_NEED || d_ws == nullptr) {
        fb_level<256, 96, 72><<<MROW, 256, 0, stream>>>(
            fm0, kp, ms0, p0_w1, p0_b1, p0_g, p0_beta, p0_w2, p0_b2,
            a0_wqkv, a0_bqkv, a0_wg, a0_bg, a0_wo, a0_bo, out0);
        fb_level<512, 48, 36><<<MROW, 512, 0, stream>>>(
            fm1, kp, ms1, p1_w1, p1_b1, p1_g, p1_beta, p1_w2, p1_b2,
            a1_wqkv, a1_bqkv, a1_wg, a1_bg, a1_wo, a1_bo, out1);
        return;
    }

    char* cur = (char*)d_ws;
    auto alloc = [&](size_t bytes) { char* p = cur; cur += (bytes + 255) & ~(size_t)255; return p; };
    u16* A1h_1 = (u16*)alloc((size_t)MPAD * 1024 * 2);
    u16* A1h_0 = (u16*)alloc((size_t)MPAD * 512 * 2);
    u16* hp_1  = (u16*)alloc((size_t)2 * MPAD * 512 * 2);   // [2][MPAD][512]
    u16* hp_0  = (u16*)alloc((size_t)2 * MPAD * 256 * 2);
    u16* qkvp_1 = (u16*)alloc((size_t)2 * MPAD * 1536 * 2); // [2][MPAD][1536]
    u16* qkvp_0 = (u16*)alloc((size_t)2 * MPAD * 768 * 2);
    u16* A4_1  = (u16*)alloc((size_t)MPAD * 1024 * 2);      // [MPAD][h16|om]
    u16* A4_0  = (u16*)alloc((size_t)MPAD * 512 * 2);
    u16* w1T_1   = (u16*)alloc((size_t)512 * 1024 * 2);
    u16* wqkvT_1 = (u16*)alloc((size_t)1536 * 512 * 2);
    u16* w24T_1  = (u16*)alloc((size_t)512 * 1024 * 2);     // [512][w2T|woT]
    u16* w1T_0   = (u16*)alloc((size_t)256 * 512 * 2);
    u16* wqkvT_0 = (u16*)alloc((size_t)768 * 256 * 2);
    u16* w24T_0  = (u16*)alloc((size_t)256 * 512 * 2);
    float* gout1 = (float*)alloc((size_t)(MROW + NKPT) * 8 * 4);
    float* gout0 = (float*)alloc((size_t)(MROW + NKPT) * 8 * 4);
    float* bsum1 = (float*)alloc(512 * 4);
    float* bsum0 = (float*)alloc(256 * 4);

    // ---- K1: pool(+gates) + meta + weight transpose/pack + bias-sum ----
    PrepP pp;
    pp.fm0 = fm0; pp.fm1 = fm1; pp.kp = kp; pp.ms0 = ms0; pp.ms1 = ms1;
    pp.wg0 = a0_wg; pp.bg0 = a0_bg; pp.wg1 = a1_wg; pp.bg1 = a1_bg;
    pp.b2_1 = p1_b2; pp.bo_1 = a1_bo; pp.b2_0 = p0_b2; pp.bo_0 = a0_bo;
    pp.A1h_0 = A1h_0; pp.A1h_1 = A1h_1;
    pp.gout0 = gout0; pp.gout1 = gout1;
    pp.bsum1 = bsum1; pp.bsum0 = bsum0;
    int tcum = 0;
    auto setTD = [&](int i, const float* src, u16* dst, int K, int N, int ld, int koff) {
        pp.td[i].src = src; pp.td[i].dst = dst; pp.td[i].K = K; pp.td[i].N = N;
        pp.td[i].ld = ld; pp.td[i].koff = koff;
        pp.td[i].blk0 = tcum; tcum += (K / 64) * (N / 64);
    };
    setTD(0, p1_w1,   w1T_1,   1024, 512,  1024, 0);
    setTD(1, a1_wqkv, wqkvT_1, 512,  1536, 512,  0);
    setTD(2, p1_w2,   w24T_1,  512,  512,  1024, 0);
    setTD(3, a1_wo,   w24T_1,  512,  512,  1024, 512);
    setTD(4, p0_w1,   w1T_0,   512,  256,  512,  0);
    setTD(5, a0_wqkv, wqkvT_0, 256,  768,  256,  0);
    setTD(6, p0_w2,   w24T_0,  256,  256,  512,  0);
    setTD(7, a0_wo,   w24T_0,  256,  256,  512,  256);
    k1_prep<<<1683, 256, 0, stream>>>(pp);   // 1088 + 34 + 560 + 1

    // ---- K2: w1 + wqkv GEMMs, split-K=2 -> fp16 part buffers (no atomics) --
    GPp g2; g2.nd = 4;
    g2.d[0] = { A1h_1, w1T_1,   p1_b1,   hp_1,   1024, 512,  1024, 512,  8,  2 };
    g2.d[1] = { A1h_1, wqkvT_1, a1_bqkv, qkvp_1, 1024, 1536, 512,  1536, 24, 2 };
    g2.d[2] = { A1h_0, w1T_0,   p0_b1,   hp_0,   512,  256,  512,  256,  4,  2 };
    g2.d[3] = { A1h_0, wqkvT_0, a0_bqkv, qkvp_0, 512,  768,  256,  768,  12, 2 };
    g2.blk0[0] = 0;
    for (int i = 0; i < 4; ++i) g2.blk0[i + 1] = g2.blk0[i] + 9 * g2.d[i].ntiles * g2.d[i].sk;
    gemm_part<<<g2.blk0[4], 256, 0, stream>>>(g2);

    // ---- K3: LN+relu -> A4 left  ||  attention -> A4 right ----
    RP rp;
    rp.hp1 = hp_1; rp.hp0 = hp_0; rp.A4_1 = A4_1; rp.A4_0 = A4_0;
    rp.g1 = p1_g; rp.be1 = p1_beta; rp.g0 = p0_g; rp.be0 = p0_beta;
    rp.qkvp1 = qkvp_1; rp.qkvp0 = qkvp_0;
    rp.gout1 = gout1; rp.gout0 = gout0;
    k3_rowops<<<2176, 256, 0, stream>>>(rp);

    // ---- K4: out = [h16|om] @ [w2T|woT]^T + (b2+bo), direct store ----
    GPo g4; g4.nd = 2;
    g4.d[0] = { A4_1, w24T_1, bsum1, out1, 1024, 512, 1024, 512, MROW, 8 };
    g4.d[1] = { A4_0, w24T_0, bsum0, out0, 512,  256, 512,  256, MROW, 4 };
    g4.blk0[0] = 0;
    for (int i = 0; i < 2; ++i) g4.blk0[i + 1] = g4.blk0[i] + 18 * g4.d[i].ntiles;
    gemm_out<<<g4.blk0[2], 256, 0, stream>>>(g4);
}

// Round 11
// 78.798 us; speedup vs baseline: 1.2481x; 1.0398x over previous
//
#include <hip/hip_runtime.h>
#include <math.h>

#define NKPT 17
#define BATCH 32
#define MROW 544          // BATCH*NKPT
#define MPAD 576          // 9*64

typedef unsigned short u16;
typedef _Float16 half8 __attribute__((ext_vector_type(8)));
typedef float f32x4 __attribute__((ext_vector_type(4)));

__device__ __forceinline__ u16 f2h(float f) {
    _Float16 h = (_Float16)f;
    u16 u; __builtin_memcpy(&u, &h, 2); return u;
}
__device__ __forceinline__ float h2f(u16 u) {
    _Float16 h; __builtin_memcpy(&h, &u, 2); return (float)h;
}

// ------------------------------------------------- GEMM -> fp16 parts -----
// BM=64, BN=64, BK=64, 256 threads (4 waves as 2x2 of 32x32), double-buffered
// LDS, one barrier per k-step. A: fp16 [MPAD][lda]. BT: fp16 [N][K].
// Split-K: part s stores DIRECTLY (fp16) to dst + s*MPAD*ldd. No atomics.
struct GDp {
    const u16* A; const u16* BT; const float* bias; u16* dst;
    int lda, ldd, K, N, ntiles, sk;
};
struct GPp { GDp d[4]; int blk0[5]; int nd; };

__global__ __launch_bounds__(256) void gemm_part(GPp P)
{
    __shared__ u16 sA[2][64][72];
    __shared__ u16 sB[2][64][72];
    int bid = blockIdx.x, gi = 0;
    while (gi + 1 < P.nd && bid >= P.blk0[gi + 1]) ++gi;
    const GDp g = P.d[gi];
    int local = bid - P.blk0[gi];
    const int nspan = g.ntiles * g.sk;
    const int mt = local / nspan;
    int rem = local - mt * nspan;
    const int nt = rem / g.sk;
    const int s  = rem - nt * g.sk;
    const int m0 = mt * 64, n0 = nt * 64;
    const int Kseg = g.K / g.sk;
    const int kbase = s * Kseg;

    const int t = threadIdx.x;
    const int l = t & 63, w = t >> 6, wr = w >> 1, wc = w & 1;
    const int row = t >> 2, kc = (t & 3) << 4;

    f32x4 acc[2][2];
    #pragma unroll
    for (int i = 0; i < 2; ++i)
        #pragma unroll
        for (int j = 0; j < 2; ++j) { f32x4 z = {0.f,0.f,0.f,0.f}; acc[i][j] = z; }

    const u16* ap = g.A  + (size_t)(m0 + row) * g.lda + kbase + kc;
    const u16* bp = g.BT + (size_t)(n0 + row) * g.K   + kbase + kc;
    uint4 ra0 = *(const uint4*)ap, ra1 = *(const uint4*)(ap + 8);
    uint4 rb0 = *(const uint4*)bp, rb1 = *(const uint4*)(bp + 8);
    *(uint4*)&sA[0][row][kc] = ra0; *(uint4*)&sA[0][row][kc + 8] = ra1;
    *(uint4*)&sB[0][row][kc] = rb0; *(uint4*)&sB[0][row][kc + 8] = rb1;
    __syncthreads();

    int cur = 0;
    for (int k0 = 0; k0 < Kseg; k0 += 64) {
        const bool nxt = (k0 + 64 < Kseg);
        if (nxt) {
            ra0 = *(const uint4*)(ap + k0 + 64); ra1 = *(const uint4*)(ap + k0 + 72);
            rb0 = *(const uint4*)(bp + k0 + 64); rb1 = *(const uint4*)(bp + k0 + 72);
        }
        #pragma unroll
        for (int ks = 0; ks < 64; ks += 32) {
            const int koff = ks + (l >> 4) * 8;
            half8 af0 = *(const half8*)&sA[cur][wr * 32 +      (l & 15)][koff];
            half8 af1 = *(const half8*)&sA[cur][wr * 32 + 16 + (l & 15)][koff];
            half8 bf0 = *(const half8*)&sB[cur][wc * 32 +      (l & 15)][koff];
            half8 bf1 = *(const half8*)&sB[cur][wc * 32 + 16 + (l & 15)][koff];
            acc[0][0] = __builtin_amdgcn_mfma_f32_16x16x32_f16(af0, bf0, acc[0][0], 0, 0, 0);
            acc[0][1] = __builtin_amdgcn_mfma_f32_16x16x32_f16(af0, bf1, acc[0][1], 0, 0, 0);
            acc[1][0] = __builtin_amdgcn_mfma_f32_16x16x32_f16(af1, bf0, acc[1][0], 0, 0, 0);
            acc[1][1] = __builtin_amdgcn_mfma_f32_16x16x32_f16(af1, bf1, acc[1][1], 0, 0, 0);
        }
        if (nxt) {
            int nb = cur ^ 1;
            *(uint4*)&sA[nb][row][kc] = ra0; *(uint4*)&sA[nb][row][kc + 8] = ra1;
            *(uint4*)&sB[nb][row][kc] = rb0; *(uint4*)&sB[nb][row][kc + 8] = rb1;
            __syncthreads();
            cur = nb;
        }
    }

    // D layout: col = l&15, row = (l>>4)*4 + reg (verified). Direct fp16 store.
    u16* dbase = g.dst + (size_t)s * MPAD * g.ldd;
    #pragma unroll
    for (int i = 0; i < 2; ++i) {
        #pragma unroll
        for (int j = 0; j < 2; ++j) {
            int col = n0 + wc * 32 + j * 16 + (l & 15);
            float bv = (s == 0) ? g.bias[col] : 0.f;
            #pragma unroll
            for (int rr = 0; rr < 4; ++rr) {
                int m = m0 + wr * 32 + i * 16 + (l >> 4) * 4 + rr;
                dbase[(size_t)m * g.ldd + col] = f2h(acc[i][j][rr] + bv);
            }
        }
    }
}

// ------------------------------------------------- GEMM -> f32 out --------
// BM=32, BN=64, BK=64. A: fp16 [MPAD][K]. BT: fp16 [N][K]. Direct f32 store.
struct GDo {
    const u16* A; const u16* BT; const float* bias; float* dst;
    int lda, ldd, K, N, mstore, ntiles;
};
struct GPo { GDo d[2]; int blk0[3]; int nd; };

__global__ __launch_bounds__(256) void gemm_out(GPo P)
{
    __shared__ u16 sA[2][32][72];
    __shared__ u16 sB[2][64][72];
    int bid = blockIdx.x, gi = 0;
    while (gi + 1 < P.nd && bid >= P.blk0[gi + 1]) ++gi;
    const GDo g = P.d[gi];
    int local = bid - P.blk0[gi];
    const int mt = local / g.ntiles, nt = local % g.ntiles;
    const int m0 = mt * 32, n0 = nt * 64;

    const int t = threadIdx.x;
    const int l = t & 63, w = t >> 6, wr = w >> 1, wc = w & 1;
    const int rowA = t >> 3, kcA = (t & 7) << 3;   // 32 rows x 8 el
    const int rowB = t >> 2, kcB = (t & 3) << 4;   // 64 rows x 16 el

    f32x4 acc[2];
    { f32x4 z = {0.f,0.f,0.f,0.f}; acc[0] = z; acc[1] = z; }

    const u16* ap = g.A  + (size_t)(m0 + rowA) * g.lda + kcA;
    const u16* bp = g.BT + (size_t)(n0 + rowB) * g.K   + kcB;
    uint4 ra  = *(const uint4*)ap;
    uint4 rb0 = *(const uint4*)bp, rb1 = *(const uint4*)(bp + 8);
    *(uint4*)&sA[0][rowA][kcA] = ra;
    *(uint4*)&sB[0][rowB][kcB] = rb0; *(uint4*)&sB[0][rowB][kcB + 8] = rb1;
    __syncthreads();

    int cur = 0;
    for (int k0 = 0; k0 < g.K; k0 += 64) {
        const bool nxt = (k0 + 64 < g.K);
        if (nxt) {
            ra  = *(const uint4*)(ap + k0 + 64);
            rb0 = *(const uint4*)(bp + k0 + 64); rb1 = *(const uint4*)(bp + k0 + 72);
        }
        #pragma unroll
        for (int ks = 0; ks < 64; ks += 32) {
            const int koff = ks + (l >> 4) * 8;
            half8 af  = *(const half8*)&sA[cur][wr * 16 + (l & 15)][koff];
            half8 bf0 = *(const half8*)&sB[cur][wc * 32 +      (l & 15)][koff];
            half8 bf1 = *(const half8*)&sB[cur][wc * 32 + 16 + (l & 15)][koff];
            acc[0] = __builtin_amdgcn_mfma_f32_16x16x32_f16(af, bf0, acc[0], 0, 0, 0);
            acc[1] = __builtin_amdgcn_mfma_f32_16x16x32_f16(af, bf1, acc[1], 0, 0, 0);
        }
        if (nxt) {
            int nb = cur ^ 1;
            *(uint4*)&sA[nb][rowA][kcA] = ra;
            *(uint4*)&sB[nb][rowB][kcB] = rb0; *(uint4*)&sB[nb][rowB][kcB + 8] = rb1;
            __syncthreads();
            cur = nb;
        }
    }

    #pragma unroll
    for (int j = 0; j < 2; ++j) {
        int col = n0 + wc * 32 + j * 16 + (l & 15);
        float bv = g.bias[col];
        #pragma unroll
        for (int rr = 0; rr < 4; ++rr) {
            int m = m0 + wr * 16 + (l >> 4) * 4 + rr;
            if (m < g.mstore)
                g.dst[(size_t)m * g.ldd + col] = acc[j][rr] + bv;
        }
    }
}

// ---------------------------------------------------------------- prep ----
struct TD { const float* src; u16* dst; int K, N, ld, koff, blk0; };
struct PrepP {
    const float *fm0, *fm1, *kp, *ms0, *ms1;
    const float *wg0, *bg0, *wg1, *bg1;
    const float *b2_1, *bo_1, *b2_0, *bo_0;
    u16 *A1h_0, *A1h_1;      // fp16 [MPAD][2C] (GEMM A)
    float *gout0, *gout1;    // [MROW+NKPT][8] sigmoid gates
    float *bsum1, *bsum0;    // b2+bo per level
    TD td[8];
};

// 8 heads x 32 lanes: gate_h = sigmoid(sx . wg[:,h] + bg[h])
__device__ void gates_from_sx(const float* sx, int C, const float* wg,
                              const float* bg, float* gout8)
{
    int t = threadIdx.x;
    int h = t >> 5, e = t & 31;
    float a = 0.f;
    for (int c = e; c < C; c += 32) a += sx[c] * wg[c * 8 + h];
    a += __shfl_xor(a, 16, 32); a += __shfl_xor(a, 8, 32);
    a += __shfl_xor(a, 4, 32);  a += __shfl_xor(a, 2, 32);
    a += __shfl_xor(a, 1, 32);
    if (e == 0) gout8[h] = 1.0f / (1.0f + expf(-(a + bg[h])));
}

// Coalesced pool: 32-lane group per channel; lanes 0..24 = window elements.
template<int C, int H, int W>
__device__ void pool_row(int b, int n, const float* fm, const float* kp,
                         const float* ms, u16* A1h, const float* wg,
                         const float* bg, float* gout, float* sx)
{
    const int t = threadIdx.x;   // 256
    const int e = t & 31, grp = t >> 5;   // 8 channel-groups
    float kx = kp[(b * NKPT + n) * 2 + 0];
    float ky = kp[(b * NKPT + n) * 2 + 1];
    int cx = (int)rintf(kx * ((float)W / 192.0f));   // RNE == jnp.round
    int cy = (int)rintf(ky * ((float)H / 256.0f));
    int dy = e / 5, dx = e % 5;
    float wgt = 0.f; int off = 0;
    if (e < 25) {
        int iy = min(max(cy + dy - 2, 0), H - 1);
        int ix = min(max(cx + dx - 2, 0), W - 1);
        off = iy * W + ix;
        wgt = expf(-(float)((dy - 2) * (dy - 2) + (dx - 2) * (dx - 2)) / 8.0f);
    }
    float ws_ = wgt;
    ws_ += __shfl_xor(ws_, 16, 32); ws_ += __shfl_xor(ws_, 8, 32);
    ws_ += __shfl_xor(ws_, 4, 32);  ws_ += __shfl_xor(ws_, 2, 32);
    ws_ += __shfl_xor(ws_, 1, 32);
    const float inv = 1.0f / ws_;

    const size_t plane = (size_t)H * W;
    const float* pf = fm + ((size_t)b * C + grp) * plane + off;
    #pragma unroll 4
    for (int c0 = grp; c0 < C; c0 += 8, pf += 8 * plane) {
        float v = 0.f;
        if (e < 25) v = wgt * (*pf);
        v += __shfl_xor(v, 16, 32); v += __shfl_xor(v, 8, 32);
        v += __shfl_xor(v, 4, 32);  v += __shfl_xor(v, 2, 32);
        v += __shfl_xor(v, 1, 32);
        if (e == 0) sx[c0] = v * inv;
    }
    __syncthreads();
    u16* rowh = A1h + (size_t)(b * NKPT + n) * (2 * C);
    for (int c = t; c < C; c += 256) {
        rowh[c] = f2h(sx[c]);
        rowh[C + c] = f2h(ms[n * C + c]);
    }
    gates_from_sx(sx, C, wg, bg, gout + (size_t)(b * NKPT + n) * 8);
}

template<int C>
__device__ void meta_row(int n, const float* ms, u16* A1h, const float* wg,
                         const float* bg, float* gout, float* sx)
{
    const int t = threadIdx.x;
    u16* rowh = A1h + (size_t)(MROW + n) * (2 * C);
    for (int c = t; c < C; c += 256) {
        float v = ms[n * C + c];
        sx[c] = v;
        rowh[c] = f2h(v);
        rowh[C + c] = 0;
    }
    __syncthreads();
    gates_from_sx(sx, C, wg, bg, gout + (size_t)(MROW + n) * 8);
}

__device__ void wtrans_tile(const TD& d, int u, float* sT)  // sT: [64][65] f32
{
    const int ntx = d.N >> 6;
    const int tk = u / ntx, tn = u % ntx;
    const int k0 = tk << 6, n0 = tn << 6;
    const int t = threadIdx.x;
    {
        int r = t >> 2, cq = (t & 3) << 4;
        const float* sp = d.src + (size_t)(k0 + r) * d.N + n0 + cq;
        #pragma unroll
        for (int i = 0; i < 4; ++i) {
            float4 v = *(const float4*)(sp + 4 * i);
            sT[r * 65 + cq + 4 * i + 0] = v.x;
            sT[r * 65 + cq + 4 * i + 1] = v.y;
            sT[r * 65 + cq + 4 * i + 2] = v.z;
            sT[r * 65 + cq + 4 * i + 3] = v.w;
        }
    }
    __syncthreads();
    {
        int nn = t >> 2, kq = (t & 3) << 4;
        u16 hv[16] __attribute__((aligned(16)));
        #pragma unroll
        for (int i = 0; i < 16; ++i) hv[i] = f2h(sT[(kq + i) * 65 + nn]);
        u16* dp = d.dst + (size_t)(n0 + nn) * d.ld + d.koff + k0 + kq;
        *reinterpret_cast<uint4*>(dp) = *reinterpret_cast<uint4*>(&hv[0]);
        *reinterpret_cast<uint4*>(dp + 8) = *reinterpret_cast<uint4*>(&hv[8]);
    }
}

__global__ __launch_bounds__(256) void k1_prep(PrepP P)
{
    __shared__ float ps[64 * 65];
    int bid = blockIdx.x;
    if (bid < 1088) {
        // XCD-locality swizzle: dispatch maps bid -> XCD as bid%8 (round-robin).
        // Give each XCD a CONTIGUOUS chunk of 136 rows = 8 complete batches, so
        // all 17 keypoints of a batch (overlapping fm windows) share one L2.
        int row = (bid & 7) * 136 + (bid >> 3);
        if (row < 544) pool_row<512, 48, 36>(row / NKPT, row % NKPT, P.fm1, P.kp, P.ms1, P.A1h_1, P.wg1, P.bg1, P.gout1, ps);
        else { int r = row - 544; pool_row<256, 96, 72>(r / NKPT, r % NKPT, P.fm0, P.kp, P.ms0, P.A1h_0, P.wg0, P.bg0, P.gout0, ps); }
    } else if (bid < 1122) {
        int u = bid - 1088;
        if (u < NKPT) meta_row<512>(u, P.ms1, P.A1h_1, P.wg1, P.bg1, P.gout1, ps);
        else          meta_row<256>(u - NKPT, P.ms0, P.A1h_0, P.wg0, P.bg0, P.gout0, ps);
    } else if (bid < 1682) {
        int u = bid - 1122, i = 0;
        while (i + 1 < 8 && u >= P.td[i + 1].blk0) ++i;
        wtrans_tile(P.td[i], u - P.td[i].blk0, ps);
    } else {
        int t = threadIdx.x;
        for (int c = t; c < 512; c += 256) P.bsum1[c] = P.b2_1[c] + P.bo_1[c];
        for (int c = t; c < 256; c += 256) P.bsum0[c] = P.b2_0[c] + P.bo_0[c];
    }
}

// ----------------------------------------------- rowops: LN+relu / attn ---
// hp: [2][MPAD][C] fp16 parts. qkvp: [2][MPAD][3C]. A4: [MPAD][2C] (h16|om).
template<int C>
__device__ void attn_row(int r, const u16* qkvp, const float* gout,
                         u16* A4, float* sred)
{
    constexpr int D = C / 8;
    constexpr int TC = 3 * C;
    const size_t PS = (size_t)MPAD * TC;
    const int t = threadIdx.x;
    const int n = r % NKPT;
    const size_t rb = (size_t)r * TC;
    const size_t mb = (size_t)(MROW + n) * TC;
    {
        int dot = t >> 3, sub = t & 7;           // 32 dots x 8 threads
        int p = dot >> 3, h = dot & 7;
        size_t qb = ((p & 2) ? mb : rb) + h * D + sub * (D / 8);
        size_t kb = ((p & 1) ? mb : rb) + C + h * D + sub * (D / 8);
        float a = 0.f;
        #pragma unroll
        for (int i = 0; i < D / 8; ++i) {
            float qv = h2f(qkvp[qb + i]) + h2f(qkvp[qb + i + PS]);
            float kv = h2f(qkvp[kb + i]) + h2f(qkvp[kb + i + PS]);
            a += qv * kv;
        }
        a += __shfl_xor(a, 4, 8); a += __shfl_xor(a, 2, 8); a += __shfl_xor(a, 1, 8);
        if (sub == 0) sred[dot] = a;
    }
    if (t >= 32 && t < 40) sred[32 + (t - 32)] = gout[(size_t)r * 8 + (t - 32)];
    else if (t >= 40 && t < 48) sred[32 + (t - 32)] = gout[(size_t)(MROW + n) * 8 + (t - 40)];
    __syncthreads();
    if (t < 8) {
        int h = t;
        float scale = (float)(1.0 / sqrt((double)D));
        float c0 = 0.f, c1 = 0.f;
        #pragma unroll
        for (int s = 0; s < 2; ++s) {
            float a0 = sred[(2 * s) * 8 + h] * scale;
            float a1 = sred[(2 * s + 1) * 8 + h] * scale;
            float mx = fmaxf(a0, a1);
            float e0 = expf(a0 - mx), e1 = expf(a1 - mx);
            float inv = 1.0f / (e0 + e1);
            float gt = sred[32 + s * 8 + h];
            c0 += e0 * inv * gt;
            c1 += e1 * inv * gt;
        }
        sred[48 + h] = 0.5f * c0;
        sred[56 + h] = 0.5f * c1;
    }
    __syncthreads();
    for (int c = t; c < C; c += 256) {
        int h = c / D;
        float v0 = h2f(qkvp[rb + 2 * C + c]) + h2f(qkvp[rb + 2 * C + c + PS]);
        float v1 = h2f(qkvp[mb + 2 * C + c]) + h2f(qkvp[mb + 2 * C + c + PS]);
        A4[(size_t)r * (2 * C) + C + c] = f2h(sred[48 + h] * v0 + sred[56 + h] * v1);
    }
}

struct RP {
    const u16 *hp1, *hp0;
    u16 *A4_1, *A4_0;
    const float *g1, *be1, *g0, *be0;
    const u16 *qkvp1, *qkvp0;
    const float *gout1, *gout0;
};
__global__ __launch_bounds__(256) void k3_rowops(RP P)
{
    __shared__ float sh[64];
    int bid = blockIdx.x;
    if (bid < 1088) {
        int lvl1 = bid < 544;
        int r = lvl1 ? bid : bid - 544;
        int C = lvl1 ? 512 : 256;
        const u16* hp = lvl1 ? P.hp1 : P.hp0;
        const size_t PSh = (size_t)MPAD * C;
        u16* A4 = (lvl1 ? P.A4_1 : P.A4_0) + (size_t)r * (2 * C);
        const float* gg = lvl1 ? P.g1 : P.g0;
        const float* bb = lvl1 ? P.be1 : P.be0;
        int t = threadIdx.x;
        int nc = C >> 8;
        float v[2] = {0.f, 0.f};
        float s1 = 0.f, s2 = 0.f;
        for (int i = 0; i < nc; ++i) {
            size_t idx = (size_t)r * C + t + (i << 8);
            float x = h2f(hp[idx]) + h2f(hp[idx + PSh]);
            v[i] = x; s1 += x; s2 += x * x;
        }
        #pragma unroll
        for (int o = 32; o > 0; o >>= 1) { s1 += __shfl_down(s1, o); s2 += __shfl_down(s2, o); }
        int lane = t & 63, wv = t >> 6;
        if (lane == 0) { sh[wv * 2] = s1; sh[wv * 2 + 1] = s2; }
        __syncthreads();
        if (t == 0) {
            float a = 0.f, b = 0.f;
            #pragma unroll
            for (int q = 0; q < 4; ++q) { a += sh[q * 2]; b += sh[q * 2 + 1]; }
            float m = a / (float)C;
            float var = b / (float)C - m * m;
            sh[8] = m; sh[9] = 1.0f / sqrtf(var + 1e-5f);
        }
        __syncthreads();
        float m = sh[8], rs = sh[9];
        for (int i = 0; i < nc; ++i) {
            int c = t + (i << 8);
            float x = (v[i] - m) * rs * gg[c] + bb[c];
            A4[c] = f2h(fmaxf(x, 0.f));
        }
    } else {
        int a = bid - 1088;
        if (a < 544) attn_row<512>(a, P.qkvp1, P.gout1, P.A4_1, sh);
        else         attn_row<256>(a - 544, P.qkvp0, P.gout0, P.A4_0, sh);
    }
}

// --------------------------------------------- fallback (round-2 kernel) --
template<int C, int H, int W>
__global__ __launch_bounds__(C) void fb_level(
    const float* __restrict__ fm, const float* __restrict__ kp,
    const float* __restrict__ ms, const float* __restrict__ w1,
    const float* __restrict__ b1, const float* __restrict__ gvec,
    const float* __restrict__ beta, const float* __restrict__ w2,
    const float* __restrict__ b2, const float* __restrict__ wqkv,
    const float* __restrict__ bqkv, const float* __restrict__ wg,
    const float* __restrict__ bg, const float* __restrict__ wo,
    const float* __restrict__ bo, float* __restrict__ out)
{
    constexpr int D = C / 8;
    constexpr int NW = C / 64;
    __shared__ float x0[C], x1[C], hbuf[C];
    __shared__ float q0[C], k0[C], v0[C], q1[C], k1[C], v1[C];
    __shared__ float om[C];
    __shared__ float gw[25];
    __shared__ float gwsum_inv;
    __shared__ float redA[NW], redB[NW];
    __shared__ float stats[2];
    __shared__ float gates[2][8];
    __shared__ float att[2][2][8];
    const int j = threadIdx.x;
    const int blk = blockIdx.x;
    const int b = blk / NKPT, n = blk % NKPT;
    if (j < 25) { int dy = j / 5 - 2, dx = j % 5 - 2; gw[j] = expf(-(float)(dy*dy+dx*dx) / 8.0f); }
    __syncthreads();
    if (j == 0) { float s = 0.f; for (int t2 = 0; t2 < 25; ++t2) s += gw[t2]; gwsum_inv = 1.0f / s; }
    float kx = kp[(b * NKPT + n) * 2 + 0];
    float ky = kp[(b * NKPT + n) * 2 + 1];
    int cx = (int)rintf(kx * ((float)W / 192.0f));
    int cy = (int)rintf(ky * ((float)H / 256.0f));
    int ix[5], iy[5];
    #pragma unroll
    for (int t2 = 0; t2 < 5; ++t2) {
        ix[t2] = min(max(cx + t2 - 2, 0), W - 1);
        iy[t2] = min(max(cy + t2 - 2, 0), H - 1);
    }
    __syncthreads();
    {
        const float* fmb = fm + ((size_t)b * C + j) * (H * W);
        float acc = 0.f;
        #pragma unroll
        for (int yy = 0; yy < 5; ++yy) {
            const float* row = fmb + iy[yy] * W;
            #pragma unroll
            for (int xx = 0; xx < 5; ++xx) acc += gw[yy * 5 + xx] * row[ix[xx]];
        }
        x0[j] = acc * gwsum_inv;
        x1[j] = ms[n * C + j];
    }
    __syncthreads();
    float hacc = b1[j];
    for (int i = 0; i < C; ++i) hacc += x0[i] * w1[i * C + j];
    for (int i = 0; i < C; ++i) hacc += x1[i] * w1[(C + i) * C + j];
    {
        float s1 = hacc, s2 = hacc * hacc;
        #pragma unroll
        for (int o = 32; o > 0; o >>= 1) { s1 += __shfl_down(s1, o); s2 += __shfl_down(s2, o); }
        int lane = j & 63, wid = j >> 6;
        if (lane == 0) { redA[wid] = s1; redB[wid] = s2; }
        __syncthreads();
        if (j == 0) {
            float t1 = 0.f, t2 = 0.f;
            for (int w = 0; w < NW; ++w) { t1 += redA[w]; t2 += redB[w]; }
            float m = t1 / (float)C, v = t2 / (float)C - m * m;
            stats[0] = m; stats[1] = 1.0f / sqrtf(v + 1e-5f);
        }
        __syncthreads();
    }
    hbuf[j] = fmaxf((hacc - stats[0]) * stats[1] * gvec[j] + beta[j], 0.f);
    __syncthreads();
    float pj = b2[j];
    for (int i = 0; i < C; ++i) pj += hbuf[i] * w2[i * C + j];
    {
        float aq0 = bqkv[j], ak0 = bqkv[C + j], av0 = bqkv[2 * C + j];
        float aq1 = aq0, ak1 = ak0, av1 = av0;
        for (int i = 0; i < C; ++i) {
            float xi0 = x0[i], xi1 = x1[i];
            const float* wr = wqkv + (size_t)i * (3 * C);
            float wq = wr[j], wk = wr[C + j], wv = wr[2 * C + j];
            aq0 += xi0 * wq; aq1 += xi1 * wq;
            ak0 += xi0 * wk; ak1 += xi1 * wk;
            av0 += xi0 * wv; av1 += xi1 * wv;
        }
        q0[j] = aq0; k0[j] = ak0; v0[j] = av0;
        q1[j] = aq1; k1[j] = ak1; v1[j] = av1;
    }
    __syncthreads();
    if (j < 16) {
        int s = j >> 3, hh = j & 7;
        const float* xs = s ? x1 : x0;
        float a = bg[hh];
        for (int i = 0; i < C; ++i) a += xs[i] * wg[i * 8 + hh];
        gates[s][hh] = 1.0f / (1.0f + expf(-a));
    }
    if (j < 32) {
        int hh = j >> 2, st = j & 3;
        const float* qs = (st & 2) ? q1 : q0;
        const float* kt = (st & 1) ? k1 : k0;
        float a = 0.f;
        for (int i = hh * D; i < (hh + 1) * D; ++i) a += qs[i] * kt[i];
        att[(st >> 1)][st & 1][hh] = a;
    }
    __syncthreads();
    if (j < 16) {
        int s = j >> 3, hh = j & 7;
        const float inv = 1.0f / sqrtf((float)D);
        float a0 = att[s][0][hh] * inv, a1 = att[s][1][hh] * inv;
        float mx = fmaxf(a0, a1);
        float e0 = expf(a0 - mx), e1 = expf(a1 - mx);
        float den = e0 + e1;
        att[s][0][hh] = e0 / den; att[s][1][hh] = e1 / den;
    }
    __syncthreads();
    {
        int hh = j / D;
        float o0 = (att[0][0][hh] * v0[j] + att[0][1][hh] * v1[j]) * gates[0][hh];
        float o1 = (att[1][0][hh] * v0[j] + att[1][1][hh] * v1[j]) * gates[1][hh];
        om[j] = 0.5f * (o0 + o1);
    }
    __syncthreads();
    float oacc = bo[j];
    for (int i = 0; i < C; ++i) oacc += om[i] * wo[i * C + j];
    out[((size_t)b * NKPT + n) * C + j] = oacc + pj;
}

// ------------------------------------------------------------- launch -----
extern "C" void kernel_launch(void* const* d_in, const int* in_sizes, int n_in,
                              void* d_out, int out_size, void* d_ws, size_t ws_size,
                              hipStream_t stream) {
    (void)in_sizes; (void)n_in; (void)out_size;
    const float* fm0  = (const float*)d_in[0];
    const float* fm1  = (const float*)d_in[1];
    const float* kp   = (const float*)d_in[2];
    const float* ms0     = (const float*)d_in[3];
    const float* p0_w1   = (const float*)d_in[4];
    const float* p0_b1   = (const float*)d_in[5];
    const float* p0_g    = (const float*)d_in[6];
    const float* p0_beta = (const float*)d_in[7];
    const float* p0_w2   = (const float*)d_in[8];
    const float* p0_b2   = (const float*)d_in[9];
    const float* a0_wqkv = (const float*)d_in[10];
    const float* a0_bqkv = (const float*)d_in[11];
    const float* a0_wg   = (const float*)d_in[12];
    const float* a0_bg   = (const float*)d_in[13];
    const float* a0_wo   = (const float*)d_in[14];
    const float* a0_bo   = (const float*)d_in[15];
    const float* ms1     = (const float*)d_in[16];
    const float* p1_w1   = (const float*)d_in[17];
    const float* p1_b1   = (const float*)d_in[18];
    const float* p1_g    = (const float*)d_in[19];
    const float* p1_beta = (const float*)d_in[20];
    const float* p1_w2   = (const float*)d_in[21];
    const float* p1_b2   = (const float*)d_in[22];
    const float* a1_wqkv = (const float*)d_in[23];
    const float* a1_bqkv = (const float*)d_in[24];
    const float* a1_wg   = (const float*)d_in[25];
    const float* a1_bg   = (const float*)d_in[26];
    const float* a1_wo   = (const float*)d_in[27];
    const float* a1_bo   = (const float*)d_in[28];

    float* out0 = (float*)d_out;                               // (544,256)
    float* out1 = (float*)d_out + (size_t)MROW * 256;          // (544,512)

    const size_t WS_NEED = 15400000;
    if (ws_size < WS_NEED || d_ws == nullptr) {
        fb_level<256, 96, 72><<<MROW, 256, 0, stream>>>(
            fm0, kp, ms0, p0_w1, p0_b1, p0_g, p0_beta, p0_w2, p0_b2,
            a0_wqkv, a0_bqkv, a0_wg, a0_bg, a0_wo, a0_bo, out0);
        fb_level<512, 48, 36><<<MROW, 512, 0, stream>>>(
            fm1, kp, ms1, p1_w1, p1_b1, p1_g, p1_beta, p1_w2, p1_b2,
            a1_wqkv, a1_bqkv, a1_wg, a1_bg, a1_wo, a1_bo, out1);
        return;
    }

    char* cur = (char*)d_ws;
    auto alloc = [&](size_t bytes) { char* p = cur; cur += (bytes + 255) & ~(size_t)255; return p; };
    u16* A1h_1 = (u16*)alloc((size_t)MPAD * 1024 * 2);
    u16* A1h_0 = (u16*)alloc((size_t)MPAD * 512 * 2);
    u16* hp_1  = (u16*)alloc((size_t)2 * MPAD * 512 * 2);   // [2][MPAD][512]
    u16* hp_0  = (u16*)alloc((size_t)2 * MPAD * 256 * 2);
    u16* qkvp_1 = (u16*)alloc((size_t)2 * MPAD * 1536 * 2); // [2][MPAD][1536]
    u16* qkvp_0 = (u16*)alloc((size_t)2 * MPAD * 768 * 2);
    u16* A4_1  = (u16*)alloc((size_t)MPAD * 1024 * 2);      // [MPAD][h16|om]
    u16* A4_0  = (u16*)alloc((size_t)MPAD * 512 * 2);
    u16* w1T_1   = (u16*)alloc((size_t)512 * 1024 * 2);
    u16* wqkvT_1 = (u16*)alloc((size_t)1536 * 512 * 2);
    u16* w24T_1  = (u16*)alloc((size_t)512 * 1024 * 2);     // [512][w2T|woT]
    u16* w1T_0   = (u16*)alloc((size_t)256 * 512 * 2);
    u16* wqkvT_0 = (u16*)alloc((size_t)768 * 256 * 2);
    u16* w24T_0  = (u16*)alloc((size_t)256 * 512 * 2);
    float* gout1 = (float*)alloc((size_t)(MROW + NKPT) * 8 * 4);
    float* gout0 = (float*)alloc((size_t)(MROW + NKPT) * 8 * 4);
    float* bsum1 = (float*)alloc(512 * 4);
    float* bsum0 = (float*)alloc(256 * 4);

    // ---- K1: pool(+gates) + meta + weight transpose/pack + bias-sum ----
    PrepP pp;
    pp.fm0 = fm0; pp.fm1 = fm1; pp.kp = kp; pp.ms0 = ms0; pp.ms1 = ms1;
    pp.wg0 = a0_wg; pp.bg0 = a0_bg; pp.wg1 = a1_wg; pp.bg1 = a1_bg;
    pp.b2_1 = p1_b2; pp.bo_1 = a1_bo; pp.b2_0 = p0_b2; pp.bo_0 = a0_bo;
    pp.A1h_0 = A1h_0; pp.A1h_1 = A1h_1;
    pp.gout0 = gout0; pp.gout1 = gout1;
    pp.bsum1 = bsum1; pp.bsum0 = bsum0;
    int tcum = 0;
    auto setTD = [&](int i, const float* src, u16* dst, int K, int N, int ld, int koff) {
        pp.td[i].src = src; pp.td[i].dst = dst; pp.td[i].K = K; pp.td[i].N = N;
        pp.td[i].ld = ld; pp.td[i].koff = koff;
        pp.td[i].blk0 = tcum; tcum += (K / 64) * (N / 64);
    };
    setTD(0, p1_w1,   w1T_1,   1024, 512,  1024, 0);
    setTD(1, a1_wqkv, wqkvT_1, 512,  1536, 512,  0);
    setTD(2, p1_w2,   w24T_1,  512,  512,  1024, 0);
    setTD(3, a1_wo,   w24T_1,  512,  512,  1024, 512);
    setTD(4, p0_w1,   w1T_0,   512,  256,  512,  0);
    setTD(5, a0_wqkv, wqkvT_0, 256,  768,  256,  0);
    setTD(6, p0_w2,   w24T_0,  256,  256,  512,  0);
    setTD(7, a0_wo,   w24T_0,  256,  256,  512,  256);
    k1_prep<<<1683, 256, 0, stream>>>(pp);   // 1088 + 34 + 560 + 1

    // ---- K2: w1 + wqkv GEMMs, split-K=2 -> fp16 part buffers (no atomics) --
    GPp g2; g2.nd = 4;
    g2.d[0] = { A1h_1, w1T_1,   p1_b1,   hp_1,   1024, 512,  1024, 512,  8,  2 };
    g2.d[1] = { A1h_1, wqkvT_1, a1_bqkv, qkvp_1, 1024, 1536, 512,  1536, 24, 2 };
    g2.d[2] = { A1h_0, w1T_0,   p0_b1,   hp_0,   512,  256,  512,  256,  4,  2 };
    g2.d[3] = { A1h_0, wqkvT_0, a0_bqkv, qkvp_0, 512,  768,  256,  768,  12, 2 };
    g2.blk0[0] = 0;
    for (int i = 0; i < 4; ++i) g2.blk0[i + 1] = g2.blk0[i] + 9 * g2.d[i].ntiles * g2.d[i].sk;
    gemm_part<<<g2.blk0[4], 256, 0, stream>>>(g2);

    // ---- K3: LN+relu -> A4 left  ||  attention -> A4 right ----
    RP rp;
    rp.hp1 = hp_1; rp.hp0 = hp_0; rp.A4_1 = A4_1; rp.A4_0 = A4_0;
    rp.g1 = p1_g; rp.be1 = p1_beta; rp.g0 = p0_g; rp.be0 = p0_beta;
    rp.qkvp1 = qkvp_1; rp.qkvp0 = qkvp_0;
    rp.gout1 = gout1; rp.gout0 = gout0;
    k3_rowops<<<2176, 256, 0, stream>>>(rp);

    // ---- K4: out = [h16|om] @ [w2T|woT]^T + (b2+bo), direct store ----
    GPo g4; g4.nd = 2;
    g4.d[0] = { A4_1, w24T_1, bsum1, out1, 1024, 512, 1024, 512, MROW, 8 };
    g4.d[1] = { A4_0, w24T_0, bsum0, out0, 512,  256, 512,  256, MROW, 4 };
    g4.blk0[0] = 0;
    for (int i = 0; i < 2; ++i) g4.blk0[i + 1] = g4.blk0[i] + 18 * g4.d[i].ntiles;
    gemm_out<<<g4.blk0[2], 256, 0, stream>>>(g4);
}

// Round 12
// 78.626 us; speedup vs baseline: 1.2509x; 1.0022x over previous
//
#include <hip/hip_runtime.h>
#include <math.h>

#define NKPT 17
#define BATCH 32
#define MROW 544          // BATCH*NKPT
#define MPAD 576          // 9*64

typedef unsigned short u16;
typedef _Float16 half8 __attribute__((ext_vector_type(8)));
typedef float f32x4 __attribute__((ext_vector_type(4)));

__device__ __forceinline__ u16 f2h(float f) {
    _Float16 h = (_Float16)f;
    u16 u; __builtin_memcpy(&u, &h, 2); return u;
}
__device__ __forceinline__ float h2f(u16 u) {
    _Float16 h; __builtin_memcpy(&h, &u, 2); return (float)h;
}

// ------------------------------------------------- GEMM -> fp16 parts -----
// BM=64, BN=64, BK=64, 256 threads (4 waves as 2x2 of 32x32), double-buffered
// LDS, one barrier per k-step. A: fp16 [MPAD][lda]. BT: fp16 [N][K].
// Split-K: part s stores DIRECTLY (fp16) to dst + s*MPAD*ldd. No atomics.
// Block remap: nt-major + XCD chunking so all blocks sharing a B panel run
// on ONE XCD's L2 (bid%8 == XCD; all blk0 offsets are %8==0).
struct GDp {
    const u16* A; const u16* BT; const float* bias; u16* dst;
    int lda, ldd, K, N, ntiles, sk;
};
struct GPp { GDp d[4]; int blk0[5]; int nd; };

__global__ __launch_bounds__(256) void gemm_part(GPp P)
{
    __shared__ u16 sA[2][64][72];
    __shared__ u16 sB[2][64][72];
    int bid = blockIdx.x, gi = 0;
    while (gi + 1 < P.nd && bid >= P.blk0[gi + 1]) ++gi;
    const GDp g = P.d[gi];
    int local = bid - P.blk0[gi];
    // XCD-chunked, nt-major tuple decode (T divisible by 8 for all gi)
    const int T = 9 * g.ntiles * g.sk;
    const int idx = (local & 7) * (T >> 3) + (local >> 3);
    const int nt = idx / (9 * g.sk);
    int rem = idx - nt * (9 * g.sk);
    const int mt = rem / g.sk;
    const int s  = rem - mt * g.sk;
    const int m0 = mt * 64, n0 = nt * 64;
    const int Kseg = g.K / g.sk;
    const int kbase = s * Kseg;

    const int t = threadIdx.x;
    const int l = t & 63, w = t >> 6, wr = w >> 1, wc = w & 1;
    const int row = t >> 2, kc = (t & 3) << 4;

    f32x4 acc[2][2];
    #pragma unroll
    for (int i = 0; i < 2; ++i)
        #pragma unroll
        for (int j = 0; j < 2; ++j) { f32x4 z = {0.f,0.f,0.f,0.f}; acc[i][j] = z; }

    const u16* ap = g.A  + (size_t)(m0 + row) * g.lda + kbase + kc;
    const u16* bp = g.BT + (size_t)(n0 + row) * g.K   + kbase + kc;
    uint4 ra0 = *(const uint4*)ap, ra1 = *(const uint4*)(ap + 8);
    uint4 rb0 = *(const uint4*)bp, rb1 = *(const uint4*)(bp + 8);
    *(uint4*)&sA[0][row][kc] = ra0; *(uint4*)&sA[0][row][kc + 8] = ra1;
    *(uint4*)&sB[0][row][kc] = rb0; *(uint4*)&sB[0][row][kc + 8] = rb1;
    __syncthreads();

    int cur = 0;
    for (int k0 = 0; k0 < Kseg; k0 += 64) {
        const bool nxt = (k0 + 64 < Kseg);
        if (nxt) {
            ra0 = *(const uint4*)(ap + k0 + 64); ra1 = *(const uint4*)(ap + k0 + 72);
            rb0 = *(const uint4*)(bp + k0 + 64); rb1 = *(const uint4*)(bp + k0 + 72);
        }
        #pragma unroll
        for (int ks = 0; ks < 64; ks += 32) {
            const int koff = ks + (l >> 4) * 8;
            half8 af0 = *(const half8*)&sA[cur][wr * 32 +      (l & 15)][koff];
            half8 af1 = *(const half8*)&sA[cur][wr * 32 + 16 + (l & 15)][koff];
            half8 bf0 = *(const half8*)&sB[cur][wc * 32 +      (l & 15)][koff];
            half8 bf1 = *(const half8*)&sB[cur][wc * 32 + 16 + (l & 15)][koff];
            acc[0][0] = __builtin_amdgcn_mfma_f32_16x16x32_f16(af0, bf0, acc[0][0], 0, 0, 0);
            acc[0][1] = __builtin_amdgcn_mfma_f32_16x16x32_f16(af0, bf1, acc[0][1], 0, 0, 0);
            acc[1][0] = __builtin_amdgcn_mfma_f32_16x16x32_f16(af1, bf0, acc[1][0], 0, 0, 0);
            acc[1][1] = __builtin_amdgcn_mfma_f32_16x16x32_f16(af1, bf1, acc[1][1], 0, 0, 0);
        }
        if (nxt) {
            int nb = cur ^ 1;
            *(uint4*)&sA[nb][row][kc] = ra0; *(uint4*)&sA[nb][row][kc + 8] = ra1;
            *(uint4*)&sB[nb][row][kc] = rb0; *(uint4*)&sB[nb][row][kc + 8] = rb1;
            __syncthreads();
            cur = nb;
        }
    }

    // D layout: col = l&15, row = (l>>4)*4 + reg (verified). Direct fp16 store.
    u16* dbase = g.dst + (size_t)s * MPAD * g.ldd;
    #pragma unroll
    for (int i = 0; i < 2; ++i) {
        #pragma unroll
        for (int j = 0; j < 2; ++j) {
            int col = n0 + wc * 32 + j * 16 + (l & 15);
            float bv = (s == 0) ? g.bias[col] : 0.f;
            #pragma unroll
            for (int rr = 0; rr < 4; ++rr) {
                int m = m0 + wr * 32 + i * 16 + (l >> 4) * 4 + rr;
                dbase[(size_t)m * g.ldd + col] = f2h(acc[i][j][rr] + bv);
            }
        }
    }
}

// ------------------------------------------------- GEMM -> f32 out --------
// BM=32, BN=64, BK=64. A: fp16 [MPAD][K]. BT: fp16 [N][K]. Direct f32 store.
// Same nt-major XCD-chunked remap (18 m-tiles; T divisible by 8).
struct GDo {
    const u16* A; const u16* BT; const float* bias; float* dst;
    int lda, ldd, K, N, mstore, ntiles;
};
struct GPo { GDo d[2]; int blk0[3]; int nd; };

__global__ __launch_bounds__(256) void gemm_out(GPo P)
{
    __shared__ u16 sA[2][32][72];
    __shared__ u16 sB[2][64][72];
    int bid = blockIdx.x, gi = 0;
    while (gi + 1 < P.nd && bid >= P.blk0[gi + 1]) ++gi;
    const GDo g = P.d[gi];
    int local = bid - P.blk0[gi];
    const int T = 18 * g.ntiles;
    const int idx = (local & 7) * (T >> 3) + (local >> 3);
    const int nt = idx / 18;
    const int mt = idx - nt * 18;
    const int m0 = mt * 32, n0 = nt * 64;

    const int t = threadIdx.x;
    const int l = t & 63, w = t >> 6, wr = w >> 1, wc = w & 1;
    const int rowA = t >> 3, kcA = (t & 7) << 3;   // 32 rows x 8 el
    const int rowB = t >> 2, kcB = (t & 3) << 4;   // 64 rows x 16 el

    f32x4 acc[2];
    { f32x4 z = {0.f,0.f,0.f,0.f}; acc[0] = z; acc[1] = z; }

    const u16* ap = g.A  + (size_t)(m0 + rowA) * g.lda + kcA;
    const u16* bp = g.BT + (size_t)(n0 + rowB) * g.K   + kcB;
    uint4 ra  = *(const uint4*)ap;
    uint4 rb0 = *(const uint4*)bp, rb1 = *(const uint4*)(bp + 8);
    *(uint4*)&sA[0][rowA][kcA] = ra;
    *(uint4*)&sB[0][rowB][kcB] = rb0; *(uint4*)&sB[0][rowB][kcB + 8] = rb1;
    __syncthreads();

    int cur = 0;
    for (int k0 = 0; k0 < g.K; k0 += 64) {
        const bool nxt = (k0 + 64 < g.K);
        if (nxt) {
            ra  = *(const uint4*)(ap + k0 + 64);
            rb0 = *(const uint4*)(bp + k0 + 64); rb1 = *(const uint4*)(bp + k0 + 72);
        }
        #pragma unroll
        for (int ks = 0; ks < 64; ks += 32) {
            const int koff = ks + (l >> 4) * 8;
            half8 af  = *(const half8*)&sA[cur][wr * 16 + (l & 15)][koff];
            half8 bf0 = *(const half8*)&sB[cur][wc * 32 +      (l & 15)][koff];
            half8 bf1 = *(const half8*)&sB[cur][wc * 32 + 16 + (l & 15)][koff];
            acc[0] = __builtin_amdgcn_mfma_f32_16x16x32_f16(af, bf0, acc[0], 0, 0, 0);
            acc[1] = __builtin_amdgcn_mfma_f32_16x16x32_f16(af, bf1, acc[1], 0, 0, 0);
        }
        if (nxt) {
            int nb = cur ^ 1;
            *(uint4*)&sA[nb][rowA][kcA] = ra;
            *(uint4*)&sB[nb][rowB][kcB] = rb0; *(uint4*)&sB[nb][rowB][kcB + 8] = rb1;
            __syncthreads();
            cur = nb;
        }
    }

    #pragma unroll
    for (int j = 0; j < 2; ++j) {
        int col = n0 + wc * 32 + j * 16 + (l & 15);
        float bv = g.bias[col];
        #pragma unroll
        for (int rr = 0; rr < 4; ++rr) {
            int m = m0 + wr * 16 + (l >> 4) * 4 + rr;
            if (m < g.mstore)
                g.dst[(size_t)m * g.ldd + col] = acc[j][rr] + bv;
        }
    }
}

// ---------------------------------------------------------------- prep ----
struct TD { const float* src; u16* dst; int K, N, ld, koff, blk0; };
struct PrepP {
    const float *fm0, *fm1, *kp, *ms0, *ms1;
    const float *wg0, *bg0, *wg1, *bg1;
    const float *b2_1, *bo_1, *b2_0, *bo_0;
    u16 *A1h_0, *A1h_1;      // fp16 [MPAD][2C] (GEMM A)
    float *gout0, *gout1;    // [MROW+NKPT][8] sigmoid gates
    float *bsum1, *bsum0;    // b2+bo per level
    TD td[8];
};

// 8 heads x 32 lanes: gate_h = sigmoid(sx . wg[:,h] + bg[h])
__device__ void gates_from_sx(const float* sx, int C, const float* wg,
                              const float* bg, float* gout8)
{
    int t = threadIdx.x;
    int h = t >> 5, e = t & 31;
    float a = 0.f;
    for (int c = e; c < C; c += 32) a += sx[c] * wg[c * 8 + h];
    a += __shfl_xor(a, 16, 32); a += __shfl_xor(a, 8, 32);
    a += __shfl_xor(a, 4, 32);  a += __shfl_xor(a, 2, 32);
    a += __shfl_xor(a, 1, 32);
    if (e == 0) gout8[h] = 1.0f / (1.0f + expf(-(a + bg[h])));
}

// Coalesced pool: 32-lane group per channel; lanes 0..24 = window elements.
template<int C, int H, int W>
__device__ void pool_row(int b, int n, const float* fm, const float* kp,
                         const float* ms, u16* A1h, const float* wg,
                         const float* bg, float* gout, float* sx)
{
    const int t = threadIdx.x;   // 256
    const int e = t & 31, grp = t >> 5;   // 8 channel-groups
    float kx = kp[(b * NKPT + n) * 2 + 0];
    float ky = kp[(b * NKPT + n) * 2 + 1];
    int cx = (int)rintf(kx * ((float)W / 192.0f));   // RNE == jnp.round
    int cy = (int)rintf(ky * ((float)H / 256.0f));
    int dy = e / 5, dx = e % 5;
    float wgt = 0.f; int off = 0;
    if (e < 25) {
        int iy = min(max(cy + dy - 2, 0), H - 1);
        int ix = min(max(cx + dx - 2, 0), W - 1);
        off = iy * W + ix;
        wgt = expf(-(float)((dy - 2) * (dy - 2) + (dx - 2) * (dx - 2)) / 8.0f);
    }
    float ws_ = wgt;
    ws_ += __shfl_xor(ws_, 16, 32); ws_ += __shfl_xor(ws_, 8, 32);
    ws_ += __shfl_xor(ws_, 4, 32);  ws_ += __shfl_xor(ws_, 2, 32);
    ws_ += __shfl_xor(ws_, 1, 32);
    const float inv = 1.0f / ws_;

    const size_t plane = (size_t)H * W;
    const float* pf = fm + ((size_t)b * C + grp) * plane + off;
    #pragma unroll 4
    for (int c0 = grp; c0 < C; c0 += 8, pf += 8 * plane) {
        float v = 0.f;
        if (e < 25) v = wgt * (*pf);
        v += __shfl_xor(v, 16, 32); v += __shfl_xor(v, 8, 32);
        v += __shfl_xor(v, 4, 32);  v += __shfl_xor(v, 2, 32);
        v += __shfl_xor(v, 1, 32);
        if (e == 0) sx[c0] = v * inv;
    }
    __syncthreads();
    u16* rowh = A1h + (size_t)(b * NKPT + n) * (2 * C);
    for (int c = t; c < C; c += 256) {
        rowh[c] = f2h(sx[c]);
        rowh[C + c] = f2h(ms[n * C + c]);
    }
    gates_from_sx(sx, C, wg, bg, gout + (size_t)(b * NKPT + n) * 8);
}

template<int C>
__device__ void meta_row(int n, const float* ms, u16* A1h, const float* wg,
                         const float* bg, float* gout, float* sx)
{
    const int t = threadIdx.x;
    u16* rowh = A1h + (size_t)(MROW + n) * (2 * C);
    for (int c = t; c < C; c += 256) {
        float v = ms[n * C + c];
        sx[c] = v;
        rowh[c] = f2h(v);
        rowh[C + c] = 0;
    }
    __syncthreads();
    gates_from_sx(sx, C, wg, bg, gout + (size_t)(MROW + n) * 8);
}

__device__ void wtrans_tile(const TD& d, int u, float* sT)  // sT: [64][65] f32
{
    const int ntx = d.N >> 6;
    const int tk = u / ntx, tn = u % ntx;
    const int k0 = tk << 6, n0 = tn << 6;
    const int t = threadIdx.x;
    {
        int r = t >> 2, cq = (t & 3) << 4;
        const float* sp = d.src + (size_t)(k0 + r) * d.N + n0 + cq;
        #pragma unroll
        for (int i = 0; i < 4; ++i) {
            float4 v = *(const float4*)(sp + 4 * i);
            sT[r * 65 + cq + 4 * i + 0] = v.x;
            sT[r * 65 + cq + 4 * i + 1] = v.y;
            sT[r * 65 + cq + 4 * i + 2] = v.z;
            sT[r * 65 + cq + 4 * i + 3] = v.w;
        }
    }
    __syncthreads();
    {
        int nn = t >> 2, kq = (t & 3) << 4;
        u16 hv[16] __attribute__((aligned(16)));
        #pragma unroll
        for (int i = 0; i < 16; ++i) hv[i] = f2h(sT[(kq + i) * 65 + nn]);
        u16* dp = d.dst + (size_t)(n0 + nn) * d.ld + d.koff + k0 + kq;
        *reinterpret_cast<uint4*>(dp) = *reinterpret_cast<uint4*>(&hv[0]);
        *reinterpret_cast<uint4*>(dp + 8) = *reinterpret_cast<uint4*>(&hv[8]);
    }
}

__global__ __launch_bounds__(256) void k1_prep(PrepP P)
{
    __shared__ float ps[64 * 65];
    int bid = blockIdx.x;
    if (bid < 1088) {
        // XCD-locality swizzle: dispatch maps bid -> XCD as bid%8 (round-robin).
        // Give each XCD a CONTIGUOUS chunk of 136 rows = 8 complete batches, so
        // all 17 keypoints of a batch (overlapping fm windows) share one L2.
        int row = (bid & 7) * 136 + (bid >> 3);
        if (row < 544) pool_row<512, 48, 36>(row / NKPT, row % NKPT, P.fm1, P.kp, P.ms1, P.A1h_1, P.wg1, P.bg1, P.gout1, ps);
        else { int r = row - 544; pool_row<256, 96, 72>(r / NKPT, r % NKPT, P.fm0, P.kp, P.ms0, P.A1h_0, P.wg0, P.bg0, P.gout0, ps); }
    } else if (bid < 1122) {
        int u = bid - 1088;
        if (u < NKPT) meta_row<512>(u, P.ms1, P.A1h_1, P.wg1, P.bg1, P.gout1, ps);
        else          meta_row<256>(u - NKPT, P.ms0, P.A1h_0, P.wg0, P.bg0, P.gout0, ps);
    } else if (bid < 1682) {
        int u = bid - 1122, i = 0;
        while (i + 1 < 8 && u >= P.td[i + 1].blk0) ++i;
        wtrans_tile(P.td[i], u - P.td[i].blk0, ps);
    } else {
        int t = threadIdx.x;
        for (int c = t; c < 512; c += 256) P.bsum1[c] = P.b2_1[c] + P.bo_1[c];
        for (int c = t; c < 256; c += 256) P.bsum0[c] = P.b2_0[c] + P.bo_0[c];
    }
}

// ----------------------------------------------- rowops: LN+relu / attn ---
// hp: [2][MPAD][C] fp16 parts. qkvp: [2][MPAD][3C]. A4: [MPAD][2C] (h16|om).
template<int C>
__device__ void attn_row(int r, const u16* qkvp, const float* gout,
                         u16* A4, float* sred)
{
    constexpr int D = C / 8;
    constexpr int TC = 3 * C;
    const size_t PS = (size_t)MPAD * TC;
    const int t = threadIdx.x;
    const int n = r % NKPT;
    const size_t rb = (size_t)r * TC;
    const size_t mb = (size_t)(MROW + n) * TC;
    {
        int dot = t >> 3, sub = t & 7;           // 32 dots x 8 threads
        int p = dot >> 3, h = dot & 7;
        size_t qb = ((p & 2) ? mb : rb) + h * D + sub * (D / 8);
        size_t kb = ((p & 1) ? mb : rb) + C + h * D + sub * (D / 8);
        float a = 0.f;
        #pragma unroll
        for (int i = 0; i < D / 8; ++i) {
            float qv = h2f(qkvp[qb + i]) + h2f(qkvp[qb + i + PS]);
            float kv = h2f(qkvp[kb + i]) + h2f(qkvp[kb + i + PS]);
            a += qv * kv;
        }
        a += __shfl_xor(a, 4, 8); a += __shfl_xor(a, 2, 8); a += __shfl_xor(a, 1, 8);
        if (sub == 0) sred[dot] = a;
    }
    if (t >= 32 && t < 40) sred[32 + (t - 32)] = gout[(size_t)r * 8 + (t - 32)];
    else if (t >= 40 && t < 48) sred[32 + (t - 32)] = gout[(size_t)(MROW + n) * 8 + (t - 40)];
    __syncthreads();
    if (t < 8) {
        int h = t;
        float scale = (float)(1.0 / sqrt((double)D));
        float c0 = 0.f, c1 = 0.f;
        #pragma unroll
        for (int s = 0; s < 2; ++s) {
            float a0 = sred[(2 * s) * 8 + h] * scale;
            float a1 = sred[(2 * s + 1) * 8 + h] * scale;
            float mx = fmaxf(a0, a1);
            float e0 = expf(a0 - mx), e1 = expf(a1 - mx);
            float inv = 1.0f / (e0 + e1);
            float gt = sred[32 + s * 8 + h];
            c0 += e0 * inv * gt;
            c1 += e1 * inv * gt;
        }
        sred[48 + h] = 0.5f * c0;
        sred[56 + h] = 0.5f * c1;
    }
    __syncthreads();
    for (int c = t; c < C; c += 256) {
        int h = c / D;
        float v0 = h2f(qkvp[rb + 2 * C + c]) + h2f(qkvp[rb + 2 * C + c + PS]);
        float v1 = h2f(qkvp[mb + 2 * C + c]) + h2f(qkvp[mb + 2 * C + c + PS]);
        A4[(size_t)r * (2 * C) + C + c] = f2h(sred[48 + h] * v0 + sred[56 + h] * v1);
    }
}

struct RP {
    const u16 *hp1, *hp0;
    u16 *A4_1, *A4_0;
    const float *g1, *be1, *g0, *be0;
    const u16 *qkvp1, *qkvp0;
    const float *gout1, *gout0;
};
__global__ __launch_bounds__(256) void k3_rowops(RP P)
{
    __shared__ float sh[64];
    int bid = blockIdx.x;
    if (bid < 1088) {
        int lvl1 = bid < 544;
        int r = lvl1 ? bid : bid - 544;
        int C = lvl1 ? 512 : 256;
        const u16* hp = lvl1 ? P.hp1 : P.hp0;
        const size_t PSh = (size_t)MPAD * C;
        u16* A4 = (lvl1 ? P.A4_1 : P.A4_0) + (size_t)r * (2 * C);
        const float* gg = lvl1 ? P.g1 : P.g0;
        const float* bb = lvl1 ? P.be1 : P.be0;
        int t = threadIdx.x;
        int nc = C >> 8;
        float v[2] = {0.f, 0.f};
        float s1 = 0.f, s2 = 0.f;
        for (int i = 0; i < nc; ++i) {
            size_t idx = (size_t)r * C + t + (i << 8);
            float x = h2f(hp[idx]) + h2f(hp[idx + PSh]);
            v[i] = x; s1 += x; s2 += x * x;
        }
        #pragma unroll
        for (int o = 32; o > 0; o >>= 1) { s1 += __shfl_down(s1, o); s2 += __shfl_down(s2, o); }
        int lane = t & 63, wv = t >> 6;
        if (lane == 0) { sh[wv * 2] = s1; sh[wv * 2 + 1] = s2; }
        __syncthreads();
        if (t == 0) {
            float a = 0.f, b = 0.f;
            #pragma unroll
            for (int q = 0; q < 4; ++q) { a += sh[q * 2]; b += sh[q * 2 + 1]; }
            float m = a / (float)C;
            float var = b / (float)C - m * m;
            sh[8] = m; sh[9] = 1.0f / sqrtf(var + 1e-5f);
        }
        __syncthreads();
        float m = sh[8], rs = sh[9];
        for (int i = 0; i < nc; ++i) {
            int c = t + (i << 8);
            float x = (v[i] - m) * rs * gg[c] + bb[c];
            A4[c] = f2h(fmaxf(x, 0.f));
        }
    } else {
        int a = bid - 1088;
        if (a < 544) attn_row<512>(a, P.qkvp1, P.gout1, P.A4_1, sh);
        else         attn_row<256>(a - 544, P.qkvp0, P.gout0, P.A4_0, sh);
    }
}

// --------------------------------------------- fallback (round-2 kernel) --
template<int C, int H, int W>
__global__ __launch_bounds__(C) void fb_level(
    const float* __restrict__ fm, const float* __restrict__ kp,
    const float* __restrict__ ms, const float* __restrict__ w1,
    const float* __restrict__ b1, const float* __restrict__ gvec,
    const float* __restrict__ beta, const float* __restrict__ w2,
    const float* __restrict__ b2, const float* __restrict__ wqkv,
    const float* __restrict__ bqkv, const float* __restrict__ wg,
    const float* __restrict__ bg, const float* __restrict__ wo,
    const float* __restrict__ bo, float* __restrict__ out)
{
    constexpr int D = C / 8;
    constexpr int NW = C / 64;
    __shared__ float x0[C], x1[C], hbuf[C];
    __shared__ float q0[C], k0[C], v0[C], q1[C], k1[C], v1[C];
    __shared__ float om[C];
    __shared__ float gw[25];
    __shared__ float gwsum_inv;
    __shared__ float redA[NW], redB[NW];
    __shared__ float stats[2];
    __shared__ float gates[2][8];
    __shared__ float att[2][2][8];
    const int j = threadIdx.x;
    const int blk = blockIdx.x;
    const int b = blk / NKPT, n = blk % NKPT;
    if (j < 25) { int dy = j / 5 - 2, dx = j % 5 - 2; gw[j] = expf(-(float)(dy*dy+dx*dx) / 8.0f); }
    __syncthreads();
    if (j == 0) { float s = 0.f; for (int t2 = 0; t2 < 25; ++t2) s += gw[t2]; gwsum_inv = 1.0f / s; }
    float kx = kp[(b * NKPT + n) * 2 + 0];
    float ky = kp[(b * NKPT + n) * 2 + 1];
    int cx = (int)rintf(kx * ((float)W / 192.0f));
    int cy = (int)rintf(ky * ((float)H / 256.0f));
    int ix[5], iy[5];
    #pragma unroll
    for (int t2 = 0; t2 < 5; ++t2) {
        ix[t2] = min(max(cx + t2 - 2, 0), W - 1);
        iy[t2] = min(max(cy + t2 - 2, 0), H - 1);
    }
    __syncthreads();
    {
        const float* fmb = fm + ((size_t)b * C + j) * (H * W);
        float acc = 0.f;
        #pragma unroll
        for (int yy = 0; yy < 5; ++yy) {
            const float* row = fmb + iy[yy] * W;
            #pragma unroll
            for (int xx = 0; xx < 5; ++xx) acc += gw[yy * 5 + xx] * row[ix[xx]];
        }
        x0[j] = acc * gwsum_inv;
        x1[j] = ms[n * C + j];
    }
    __syncthreads();
    float hacc = b1[j];
    for (int i = 0; i < C; ++i) hacc += x0[i] * w1[i * C + j];
    for (int i = 0; i < C; ++i) hacc += x1[i] * w1[(C + i) * C + j];
    {
        float s1 = hacc, s2 = hacc * hacc;
        #pragma unroll
        for (int o = 32; o > 0; o >>= 1) { s1 += __shfl_down(s1, o); s2 += __shfl_down(s2, o); }
        int lane = j & 63, wid = j >> 6;
        if (lane == 0) { redA[wid] = s1; redB[wid] = s2; }
        __syncthreads();
        if (j == 0) {
            float t1 = 0.f, t2 = 0.f;
            for (int w = 0; w < NW; ++w) { t1 += redA[w]; t2 += redB[w]; }
            float m = t1 / (float)C, v = t2 / (float)C - m * m;
            stats[0] = m; stats[1] = 1.0f / sqrtf(v + 1e-5f);
        }
        __syncthreads();
    }
    hbuf[j] = fmaxf((hacc - stats[0]) * stats[1] * gvec[j] + beta[j], 0.f);
    __syncthreads();
    float pj = b2[j];
    for (int i = 0; i < C; ++i) pj += hbuf[i] * w2[i * C + j];
    {
        float aq0 = bqkv[j], ak0 = bqkv[C + j], av0 = bqkv[2 * C + j];
        float aq1 = aq0, ak1 = ak0, av1 = av0;
        for (int i = 0; i < C; ++i) {
            float xi0 = x0[i], xi1 = x1[i];
            const float* wr = wqkv + (size_t)i * (3 * C);
            float wq = wr[j], wk = wr[C + j], wv = wr[2 * C + j];
            aq0 += xi0 * wq; aq1 += xi1 * wq;
            ak0 += xi0 * wk; ak1 += xi1 * wk;
            av0 += xi0 * wv; av1 += xi1 * wv;
        }
        q0[j] = aq0; k0[j] = ak0; v0[j] = av0;
        q1[j] = aq1; k1[j] = ak1; v1[j] = av1;
    }
    __syncthreads();
    if (j < 16) {
        int s = j >> 3, hh = j & 7;
        const float* xs = s ? x1 : x0;
        float a = bg[hh];
        for (int i = 0; i < C; ++i) a += xs[i] * wg[i * 8 + hh];
        gates[s][hh] = 1.0f / (1.0f + expf(-a));
    }
    if (j < 32) {
        int hh = j >> 2, st = j & 3;
        const float* qs = (st & 2) ? q1 : q0;
        const float* kt = (st & 1) ? k1 : k0;
        float a = 0.f;
        for (int i = hh * D; i < (hh + 1) * D; ++i) a += qs[i] * kt[i];
        att[(st >> 1)][st & 1][hh] = a;
    }
    __syncthreads();
    if (j < 16) {
        int s = j >> 3, hh = j & 7;
        const float inv = 1.0f / sqrtf((float)D);
        float a0 = att[s][0][hh] * inv, a1 = att[s][1][hh] * inv;
        float mx = fmaxf(a0, a1);
        float e0 = expf(a0 - mx), e1 = expf(a1 - mx);
        float den = e0 + e1;
        att[s][0][hh] = e0 / den; att[s][1][hh] = e1 / den;
    }
    __syncthreads();
    {
        int hh = j / D;
        float o0 = (att[0][0][hh] * v0[j] + att[0][1][hh] * v1[j]) * gates[0][hh];
        float o1 = (att[1][0][hh] * v0[j] + att[1][1][hh] * v1[j]) * gates[1][hh];
        om[j] = 0.5f * (o0 + o1);
    }
    __syncthreads();
    float oacc = bo[j];
    for (int i = 0; i < C; ++i) oacc += om[i] * wo[i * C + j];
    out[((size_t)b * NKPT + n) * C + j] = oacc + pj;
}

// ------------------------------------------------------------- launch -----
extern "C" void kernel_launch(void* const* d_in, const int* in_sizes, int n_in,
                              void* d_out, int out_size, void* d_ws, size_t ws_size,
                              hipStream_t stream) {
    (void)in_sizes; (void)n_in; (void)out_size;
    const float* fm0  = (const float*)d_in[0];
    const float* fm1  = (const float*)d_in[1];
    const float* kp   = (const float*)d_in[2];
    const float* ms0     = (const float*)d_in[3];
    const float* p0_w1   = (const float*)d_in[4];
    const float* p0_b1   = (const float*)d_in[5];
    const float* p0_g    = (const float*)d_in[6];
    const float* p0_beta = (const float*)d_in[7];
    const float* p0_w2   = (const float*)d_in[8];
    const float* p0_b2   = (const float*)d_in[9];
    const float* a0_wqkv = (const float*)d_in[10];
    const float* a0_bqkv = (const float*)d_in[11];
    const float* a0_wg   = (const float*)d_in[12];
    const float* a0_bg   = (const float*)d_in[13];
    const float* a0_wo   = (const float*)d_in[14];
    const float* a0_bo   = (const float*)d_in[15];
    const float* ms1     = (const float*)d_in[16];
    const float* p1_w1   = (const float*)d_in[17];
    const float* p1_b1   = (const float*)d_in[18];
    const float* p1_g    = (const float*)d_in[19];
    const float* p1_beta = (const float*)d_in[20];
    const float* p1_w2   = (const float*)d_in[21];
    const float* p1_b2   = (const float*)d_in[22];
    const float* a1_wqkv = (const float*)d_in[23];
    const float* a1_bqkv = (const float*)d_in[24];
    const float* a1_wg   = (const float*)d_in[25];
    const float* a1_bg   = (const float*)d_in[26];
    const float* a1_wo   = (const float*)d_in[27];
    const float* a1_bo   = (const float*)d_in[28];

    float* out0 = (float*)d_out;                               // (544,256)
    float* out1 = (float*)d_out + (size_t)MROW * 256;          // (544,512)

    const size_t WS_NEED = 15400000;
    if (ws_size < WS_NEED || d_ws == nullptr) {
        fb_level<256, 96, 72><<<MROW, 256, 0, stream>>>(
            fm0, kp, ms0, p0_w1, p0_b1, p0_g, p0_beta, p0_w2, p0_b2,
            a0_wqkv, a0_bqkv, a0_wg, a0_bg, a0_wo, a0_bo, out0);
        fb_level<512, 48, 36><<<MROW, 512, 0, stream>>>(
            fm1, kp, ms1, p1_w1, p1_b1, p1_g, p1_beta, p1_w2, p1_b2,
            a1_wqkv, a1_bqkv, a1_wg, a1_bg, a1_wo, a1_bo, out1);
        return;
    }

    char* cur = (char*)d_ws;
    auto alloc = [&](size_t bytes) { char* p = cur; cur += (bytes + 255) & ~(size_t)255; return p; };
    u16* A1h_1 = (u16*)alloc((size_t)MPAD * 1024 * 2);
    u16* A1h_0 = (u16*)alloc((size_t)MPAD * 512 * 2);
    u16* hp_1  = (u16*)alloc((size_t)2 * MPAD * 512 * 2);   // [2][MPAD][512]
    u16* hp_0  = (u16*)alloc((size_t)2 * MPAD * 256 * 2);
    u16* qkvp_1 = (u16*)alloc((size_t)2 * MPAD * 1536 * 2); // [2][MPAD][1536]
    u16* qkvp_0 = (u16*)alloc((size_t)2 * MPAD * 768 * 2);
    u16* A4_1  = (u16*)alloc((size_t)MPAD * 1024 * 2);      // [MPAD][h16|om]
    u16* A4_0  = (u16*)alloc((size_t)MPAD * 512 * 2);
    u16* w1T_1   = (u16*)alloc((size_t)512 * 1024 * 2);
    u16* wqkvT_1 = (u16*)alloc((size_t)1536 * 512 * 2);
    u16* w24T_1  = (u16*)alloc((size_t)512 * 1024 * 2);     // [512][w2T|woT]
    u16* w1T_0   = (u16*)alloc((size_t)256 * 512 * 2);
    u16* wqkvT_0 = (u16*)alloc((size_t)768 * 256 * 2);
    u16* w24T_0  = (u16*)alloc((size_t)256 * 512 * 2);
    float* gout1 = (float*)alloc((size_t)(MROW + NKPT) * 8 * 4);
    float* gout0 = (float*)alloc((size_t)(MROW + NKPT) * 8 * 4);
    float* bsum1 = (float*)alloc(512 * 4);
    float* bsum0 = (float*)alloc(256 * 4);

    // ---- K1: pool(+gates) + meta + weight transpose/pack + bias-sum ----
    PrepP pp;
    pp.fm0 = fm0; pp.fm1 = fm1; pp.kp = kp; pp.ms0 = ms0; pp.ms1 = ms1;
    pp.wg0 = a0_wg; pp.bg0 = a0_bg; pp.wg1 = a1_wg; pp.bg1 = a1_bg;
    pp.b2_1 = p1_b2; pp.bo_1 = a1_bo; pp.b2_0 = p0_b2; pp.bo_0 = a0_bo;
    pp.A1h_0 = A1h_0; pp.A1h_1 = A1h_1;
    pp.gout0 = gout0; pp.gout1 = gout1;
    pp.bsum1 = bsum1; pp.bsum0 = bsum0;
    int tcum = 0;
    auto setTD = [&](int i, const float* src, u16* dst, int K, int N, int ld, int koff) {
        pp.td[i].src = src; pp.td[i].dst = dst; pp.td[i].K = K; pp.td[i].N = N;
        pp.td[i].ld = ld; pp.td[i].koff = koff;
        pp.td[i].blk0 = tcum; tcum += (K / 64) * (N / 64);
    };
    setTD(0, p1_w1,   w1T_1,   1024, 512,  1024, 0);
    setTD(1, a1_wqkv, wqkvT_1, 512,  1536, 512,  0);
    setTD(2, p1_w2,   w24T_1,  512,  512,  1024, 0);
    setTD(3, a1_wo,   w24T_1,  512,  512,  1024, 512);
    setTD(4, p0_w1,   w1T_0,   512,  256,  512,  0);
    setTD(5, a0_wqkv, wqkvT_0, 256,  768,  256,  0);
    setTD(6, p0_w2,   w24T_0,  256,  256,  512,  0);
    setTD(7, a0_wo,   w24T_0,  256,  256,  512,  256);
    k1_prep<<<1683, 256, 0, stream>>>(pp);   // 1088 + 34 + 560 + 1

    // ---- K2: w1 + wqkv GEMMs, split-K=2 -> fp16 part buffers (no atomics) --
    GPp g2; g2.nd = 4;
    g2.d[0] = { A1h_1, w1T_1,   p1_b1,   hp_1,   1024, 512,  1024, 512,  8,  2 };
    g2.d[1] = { A1h_1, wqkvT_1, a1_bqkv, qkvp_1, 1024, 1536, 512,  1536, 24, 2 };
    g2.d[2] = { A1h_0, w1T_0,   p0_b1,   hp_0,   512,  256,  512,  256,  4,  2 };
    g2.d[3] = { A1h_0, wqkvT_0, a0_bqkv, qkvp_0, 512,  768,  256,  768,  12, 2 };
    g2.blk0[0] = 0;
    for (int i = 0; i < 4; ++i) g2.blk0[i + 1] = g2.blk0[i] + 9 * g2.d[i].ntiles * g2.d[i].sk;
    gemm_part<<<g2.blk0[4], 256, 0, stream>>>(g2);

    // ---- K3: LN+relu -> A4 left  ||  attention -> A4 right ----
    RP rp;
    rp.hp1 = hp_1; rp.hp0 = hp_0; rp.A4_1 = A4_1; rp.A4_0 = A4_0;
    rp.g1 = p1_g; rp.be1 = p1_beta; rp.g0 = p0_g; rp.be0 = p0_beta;
    rp.qkvp1 = qkvp_1; rp.qkvp0 = qkvp_0;
    rp.gout1 = gout1; rp.gout0 = gout0;
    k3_rowops<<<2176, 256, 0, stream>>>(rp);

    // ---- K4: out = [h16|om] @ [w2T|woT]^T + (b2+bo), direct store ----
    GPo g4; g4.nd = 2;
    g4.d[0] = { A4_1, w24T_1, bsum1, out1, 1024, 512, 1024, 512, MROW, 8 };
    g4.d[1] = { A4_0, w24T_0, bsum0, out0, 512,  256, 512,  256, MROW, 4 };
    g4.blk0[0] = 0;
    for (int i = 0; i < 2; ++i) g4.blk0[i + 1] = g4.blk0[i] + 18 * g4.d[i].ntiles;
    gemm_out<<<g4.blk0[2], 256, 0, stream>>>(g4);
}